// Round 11
// baseline (164.878 us; speedup 1.0000x reference)
//
#include <hip/hip_runtime.h>
#include <cstdint>
#include <cstddef>

#define NN   2048
#define N2   (2048LL*2048LL)
#define CC   2
#define EE   5
#define WIN  512
#define WOUT 256

typedef __bf16 bf16_t;
typedef __attribute__((ext_vector_type(8))) __bf16 bf16x8;
typedef __attribute__((ext_vector_type(4))) __bf16 bf16x4;
typedef __attribute__((ext_vector_type(4))) float  f32x4;

#define AS1 __attribute__((address_space(1)))
#define AS3 __attribute__((address_space(3)))

// ---------------- combine (+merged prep): single A pass; Hb via LDS, Hb2 in registers ----------------
// grid: 1024 combine blocks + 640 prep blocks (1D, 1664)

__global__ void k_combine(const float* __restrict__ A,
                          const float* __restrict__ w0a, const float* __restrict__ w0b,
                          const float* __restrict__ w1,
                          bf16_t* __restrict__ Ha, bf16_t* __restrict__ HbT,
                          bf16_t* __restrict__ Hb2T, float* __restrict__ part,
                          const float* __restrict__ X, const float* __restrict__ l1w,
                          const float* __restrict__ l2w, const float* __restrict__ gcnw,
                          bf16_t* __restrict__ Xb, bf16_t* __restrict__ l1wb,
                          bf16_t* __restrict__ l2wb, bf16_t* __restrict__ gwT) {
  __shared__ bf16_t tl[2][64][65];   // 16.6 KB
  __shared__ float cs[2][4][64];     // 2 KB (per-wave colsum partials)
  int bid = blockIdx.x;
  int t = threadIdx.x;

  if (bid >= 1024) {
    // ---- prep path ----
    int bid2 = bid - 1024;
    if (bid2 < 608) {
      int i = bid2 * 256 + t;
      const float* src; bf16_t* dst; int off;
      if (i < 131072)      { src = X;   dst = Xb;   off = i; }
      else if (i < 147456) { src = l1w; dst = l1wb; off = i - 131072; }
      else                 { src = l2w; dst = l2wb; off = i - 147456; }
      float4 a = ((const float4*)src)[off * 2];
      float4 b = ((const float4*)src)[off * 2 + 1];
      bf16x8 o;
      o[0] = (bf16_t)a.x; o[1] = (bf16_t)a.y; o[2] = (bf16_t)a.z; o[3] = (bf16_t)a.w;
      o[4] = (bf16_t)b.x; o[5] = (bf16_t)b.y; o[6] = (bf16_t)b.z; o[7] = (bf16_t)b.w;
      ((bf16x8*)dst)[off] = o;
    } else {
      int b2 = bid2 - 608;             // 0..31
      int m0 = (b2 & 7) * 64, n0 = (b2 >> 3) * 64;
      int tr = t >> 4, tc = (t & 15) << 2;
      bf16_t (*tile)[65] = (bf16_t (*)[65])&tl[0][0][0];
#pragma unroll
      for (int v = 0; v < 4; ++v) {
        int r = tr + v * 16;
        float4 d = *(const float4*)&gcnw[(long long)(m0 + r) * WOUT + n0 + tc];
        tile[r][tc + 0] = (bf16_t)d.x; tile[r][tc + 1] = (bf16_t)d.y;
        tile[r][tc + 2] = (bf16_t)d.z; tile[r][tc + 3] = (bf16_t)d.w;
      }
      __syncthreads();
#pragma unroll
      for (int v = 0; v < 4; ++v) {
        int r = tr + v * 16;
        bf16x4 o;
        o[0] = tile[tc + 0][r]; o[1] = tile[tc + 1][r];
        o[2] = tile[tc + 2][r]; o[3] = tile[tc + 3][r];
        *(bf16x4*)&gwT[(long long)(n0 + r) * WIN + m0 + tc] = o;
      }
    }
    return;
  }

  // ---- combine path ----
  float f[3][2][5];
  {
    const float* wp[3] = {w0a, w0b, w1};
#pragma unroll
    for (int w = 0; w < 3; ++w)
#pragma unroll
      for (int c = 0; c < 2; ++c) {
        float x[5], m = -1e30f, s = 0.f;
#pragma unroll
        for (int e = 0; e < 5; ++e) { x[e] = wp[w][c * 5 + e]; m = fmaxf(m, x[e]); }
#pragma unroll
        for (int e = 0; e < 5; ++e) { x[e] = expf(x[e] - m); s += x[e]; }
#pragma unroll
        for (int e = 0; e < 5; ++e) f[w][c][e] = x[e] / s;
      }
  }
  int i0 = (bid >> 5) * 64, j0 = (bid & 31) * 64;
  int tr = t >> 4, tc = (t & 15) << 2;
  int lane = t & 63, wid = t >> 6;
  float cs0[4] = {0, 0, 0, 0}, cs1[4] = {0, 0, 0, 0};
  bf16x4 hb2a[4], hb2b[4];

#pragma unroll
  for (int v = 0; v < 4; ++v) {
    int lr = tr + v * 16;
    long long gi = i0 + lr;
    const float* base = A + gi * (long long)NN + j0 + tc;
    float av[5][4];
#pragma unroll
    for (int e = 0; e < 5; ++e) {
      float4 q = *(const float4*)(base + (long long)e * N2);
      av[e][0] = q.x; av[e][1] = q.y; av[e][2] = q.z; av[e][3] = q.w;
    }
    bf16x4 ha0, ha1;
#pragma unroll
    for (int x = 0; x < 4; ++x) {
      float s0 = 0.f, s1 = 0.f, s2 = 0.f, s3 = 0.f, s4 = 0.f, s5 = 0.f;
#pragma unroll
      for (int e = 0; e < 5; ++e) {
        float u = av[e][x];
        s0 += f[0][0][e] * u; s1 += f[0][1][e] * u;
        s2 += f[1][0][e] * u; s3 += f[1][1][e] * u;
        s4 += f[2][0][e] * u; s5 += f[2][1][e] * u;
      }
      ha0[x] = (bf16_t)s0; cs0[x] += (float)ha0[x];
      ha1[x] = (bf16_t)s1; cs1[x] += (float)ha1[x];
      tl[0][lr][tc + x] = (bf16_t)s2; tl[1][lr][tc + x] = (bf16_t)s3;
      hb2a[v][x] = (bf16_t)s4; hb2b[v][x] = (bf16_t)s5;
    }
    *(bf16x4*)&Ha[0 * N2 + gi * NN + j0 + tc] = ha0;
    *(bf16x4*)&Ha[1 * N2 + gi * NN + j0 + tc] = ha1;
  }
  // intra-wave reduce over lane>>4 (4 of the 16 row-groups per wave), then LDS
#pragma unroll
  for (int x = 0; x < 4; ++x) {
    float a0 = cs0[x], a1 = cs1[x];
    a0 += __shfl_xor(a0, 16, 64); a0 += __shfl_xor(a0, 32, 64);
    a1 += __shfl_xor(a1, 16, 64); a1 += __shfl_xor(a1, 32, 64);
    if ((lane >> 4) == 0) {
      cs[0][wid][(lane & 15) * 4 + x] = a0;
      cs[1][wid][(lane & 15) * 4 + x] = a1;
    }
  }
  __syncthreads();

#pragma unroll
  for (int v = 0; v < 4; ++v) {
    int lr = tr + v * 16;
#pragma unroll
    for (int ch = 0; ch < 2; ++ch) {
      bf16x4 o;
      o[0] = tl[ch][tc + 0][lr]; o[1] = tl[ch][tc + 1][lr];
      o[2] = tl[ch][tc + 2][lr]; o[3] = tl[ch][tc + 3][lr];
      *(bf16x4*)&HbT[(long long)ch * N2 + (long long)(j0 + lr) * NN + i0 + tc] = o;
    }
  }
  if (t < 128) {
    int ch = t >> 6, col = t & 63;
    float s = cs[ch][0][col] + cs[ch][1][col] + cs[ch][2][col] + cs[ch][3][col];
    part[((long long)ch * 32 + (bid >> 5)) * NN + j0 + col] = s;
  }
  __syncthreads();

#pragma unroll
  for (int v = 0; v < 4; ++v) {
    int lr = tr + v * 16;
#pragma unroll
    for (int x = 0; x < 4; ++x) {
      tl[0][lr][tc + x] = hb2a[v][x];
      tl[1][lr][tc + x] = hb2b[v][x];
    }
  }
  __syncthreads();

#pragma unroll
  for (int v = 0; v < 4; ++v) {
    int lr = tr + v * 16;
#pragma unroll
    for (int ch = 0; ch < 2; ++ch) {
      bf16x4 o;
      o[0] = tl[ch][tc + 0][lr]; o[1] = tl[ch][tc + 1][lr];
      o[2] = tl[ch][tc + 2][lr]; o[3] = tl[ch][tc + 3][lr];
      *(bf16x4*)&Hb2T[(long long)ch * N2 + (long long)(j0 + lr) * NN + i0 + tc] = o;
    }
  }
}

__global__ void k_s_finish(const float* __restrict__ part, float* __restrict__ s) {
  int idx = blockIdx.x * 256 + threadIdx.x;
  int c = idx >> 11, k = idx & 2047;
  float acc = 0.f;
#pragma unroll
  for (int ib = 0; ib < 32; ++ib) acc += part[((long long)c * 32 + ib) * NN + k];
  s[idx] = acc;
}

// deg[c][j] = sum_k (svec[k] - A[j,k])*BT[j,k];  Mdiag[c][j] = sum_k A[j,k]*BT[j,k]
template<bool EMIT_DIS>
__global__ void k_deg(const float* __restrict__ svec, const bf16_t* __restrict__ Arows,
                      const bf16_t* __restrict__ BT,
                      float* __restrict__ out1, float* __restrict__ out2,
                      float* __restrict__ out3) {
  int c = blockIdx.y;
  int j = blockIdx.x * 4 + (threadIdx.x >> 6);
  int lane = threadIdx.x & 63;
  const bf16_t* a = Arows + (long long)c * N2 + (long long)j * NN;
  const bf16_t* b = BT + (long long)c * N2 + (long long)j * NN;
  const float* s = svec + c * NN;
  float acc_s = 0.f, acc_a = 0.f;
#pragma unroll
  for (int it = 0; it < 4; ++it) {
    int k0 = (lane + it * 64) * 8;
    bf16x8 av = *(const bf16x8*)(a + k0);
    bf16x8 bv = *(const bf16x8*)(b + k0);
    float4 s0 = *(const float4*)(s + k0);
    float4 s1 = *(const float4*)(s + k0 + 4);
    float sv[8] = {s0.x, s0.y, s0.z, s0.w, s1.x, s1.y, s1.z, s1.w};
#pragma unroll
    for (int x = 0; x < 8; ++x) {
      float bx = (float)bv[x];
      acc_s += sv[x] * bx;
      acc_a += (float)av[x] * bx;
    }
  }
#pragma unroll
  for (int o = 32; o > 0; o >>= 1) {
    acc_s += __shfl_xor(acc_s, o, 64);
    acc_a += __shfl_xor(acc_a, o, 64);
  }
  if (lane == 0) {
    float deg = acc_s - acc_a;
    bool nz = (deg != 0.f);
    if (!EMIT_DIS) {
      out1[c * NN + j] = nz ? 1.f / deg : 0.f;
      out2[c * NN + j] = nz ? 1.f : 0.f;
    } else {
      float dis = nz ? 0.70710678118654752f : 1.f;
      out1[c * NN + j] = nz ? dis / deg : 0.f;     // cscal
      out2[c * NN + j] = dis;                      // disv
      out3[c * NN + j] = acc_a;                    // Mdiag
    }
  }
}

// ---------------- GEMM1: 128x128 tile, BARRIER-FREE wave-private LDS ----------------
// 4 waves (2x2), wave tile 64x64; each wave stages its own A-rows + B-rows into a
// private ring-2 of BK32 slots (16 KB/wave, 64 KB/block -> 2 blocks/CU).
// Sync is per-wave only: vmcnt(8) for slot readiness, lgkmcnt(0) before slot reuse.

__global__ __launch_bounds__(256)
void k_gemmL(const bf16_t* __restrict__ A, const bf16_t* __restrict__ B,
             bf16_t* __restrict__ Hn, bf16_t* __restrict__ HnT,
             const float* __restrict__ dinv) {
  __shared__ __align__(16) char smem[65536];
  bf16_t* tile = (bf16_t*)smem;   // epilogue reuse: 128x130 bf16 = 33.3 KB

  int cz = blockIdx.z;
  const bf16_t* Abase = A + cz * N2 + (long long)blockIdx.x * 128 * NN;
  const bf16_t* Bbase = B + cz * N2 + (long long)blockIdx.y * 128 * NN;

  int t = threadIdx.x, wid = t >> 6, lane = t & 63;
  int wr = wid >> 1, wc = wid & 1;
  f32x4 acc[4][4] = {};
  int frow = lane & 15;
  int fk_sw = (((lane >> 4) ^ ((frow >> 1) & 3)) << 3);
  // stage: lane -> row (lane>>2), LDS chunk (lane&3); source global chunk pre-swizzled
  int srw = lane >> 2;                               // 0..15, +16 per gload
  int chunk_sw = ((lane & 3) ^ ((lane >> 3) & 3));   // (row>>1)&3 invariant across 16-row steps
  // per-lane global sources (row-relative to the wave's private 64-row panels)
  const bf16_t* Aw = Abase + (long long)(wr * 64 + srw) * NN + chunk_sw * 8;
  const bf16_t* Bw = Bbase + (long long)(wc * 64 + srw) * NN + chunk_sw * 8;
  char* lds0 = smem + wid * 16384;                   // wave-private: 2 bufs x (4KB A + 4KB B)

  auto STAGE = [&](int TT, int BUF) {
    long long kk = (long long)TT * 32;
    char* la = lds0 + BUF * 8192;
    char* lb = la + 4096;
#pragma unroll
    for (int gl = 0; gl < 4; ++gl) {
      __builtin_amdgcn_global_load_lds((AS1 void*)(Aw + (long long)(gl * 16) * NN + kk),
          (AS3 void*)(la + gl * 1024), 16, 0, 0);
      __builtin_amdgcn_global_load_lds((AS1 void*)(Bw + (long long)(gl * 16) * NN + kk),
          (AS3 void*)(lb + gl * 1024), 16, 0, 0);
    }
  };

  const int nt = 64;  // K / 32
  STAGE(0, 0); STAGE(1, 1);
  for (int tt = 0; tt < nt; ++tt) {
    if (tt < nt - 1) asm volatile("s_waitcnt vmcnt(8)" ::: "memory");
    else             asm volatile("s_waitcnt vmcnt(0)" ::: "memory");
    __builtin_amdgcn_sched_barrier(0);
    const bf16_t* As = (const bf16_t*)(lds0 + (tt & 1) * 8192);
    const bf16_t* Bs = As + 2048;
    bf16x8 af[4], bfr[4];
#pragma unroll
    for (int m = 0; m < 4; ++m)
      af[m] = *(const bf16x8*)&As[(m * 16 + frow) * 32 + fk_sw];
#pragma unroll
    for (int n = 0; n < 4; ++n)
      bfr[n] = *(const bf16x8*)&Bs[(n * 16 + frow) * 32 + fk_sw];
    asm volatile("s_waitcnt lgkmcnt(0)" ::: "memory");  // frags in regs before slot reuse
    __builtin_amdgcn_sched_barrier(0);
    if (tt + 2 < nt) STAGE(tt + 2, tt & 1);
    __builtin_amdgcn_s_setprio(1);
#pragma unroll
    for (int m = 0; m < 4; ++m)
#pragma unroll
      for (int n = 0; n < 4; ++n)
        acc[m][n] = __builtin_amdgcn_mfma_f32_16x16x32_bf16(af[m], bfr[n], acc[m][n], 0, 0, 0);
    __builtin_amdgcn_s_setprio(0);
  }
  __builtin_amdgcn_sched_barrier(0);

  int rl0 = wr * 64 + ((lane >> 4) << 2);
  int cl0 = wc * 64 + (lane & 15);
  int r0 = blockIdx.x * 128 + rl0;
  int c0 = blockIdx.y * 128 + cl0;

  bf16_t* Cb = Hn + cz * N2;
  bf16_t* Ct = HnT + cz * N2;
  float dj[4];
#pragma unroll
  for (int n = 0; n < 4; ++n) dj[n] = dinv[cz * NN + c0 + n * 16];
  __syncthreads();  // all waves done with private LDS before tile reuse
#pragma unroll
  for (int m = 0; m < 4; ++m)
#pragma unroll
    for (int n = 0; n < 4; ++n)
#pragma unroll
      for (int j = 0; j < 4; ++j) {
        int r = r0 + m * 16 + j, col = c0 + n * 16;
        float v = (r == col) ? 0.f : acc[m][n][j] * dj[n];
        Cb[(long long)r * NN + col] = (bf16_t)v;
        tile[(rl0 + m * 16 + j) * 130 + cl0 + n * 16] = (bf16_t)v;
      }
  __syncthreads();
  int nl = t >> 5, rl = (t & 31) * 4;
#pragma unroll
  for (int vv = 0; vv < 16; ++vv) {
    int n_l = nl + vv * 8;
    bf16x4 o;
    o[0] = tile[(rl + 0) * 130 + n_l]; o[1] = tile[(rl + 1) * 130 + n_l];
    o[2] = tile[(rl + 2) * 130 + n_l]; o[3] = tile[(rl + 3) * 130 + n_l];
    *(bf16x4*)&Ct[(long long)(blockIdx.y * 128 + n_l) * NN + blockIdx.x * 128 + rl] = o;
  }
}

// ---------------- bf16 GEMM, 128x64 tile, ring-3, counted vmcnt, swizzle, fused epilogues ----------------

enum { EP_BRELU = 3, EP_BF32 = 4, EP_BF16O = 7, EP_XWDT = 8, EP_GCN = 9 };

template<int EP>
__global__ __launch_bounds__(256)
void k_gemm(const bf16_t* __restrict__ A, const bf16_t* __restrict__ B,
            void* __restrict__ Cv,
            const float* __restrict__ aux1, const float* __restrict__ aux2,
            bf16_t* __restrict__ aux3, const float* __restrict__ aux4,
            int N, int K, int lda, int ldb,
            long long zA, long long zB, long long zC) {
  __shared__ __align__(16) char smem[36864];
  bf16_t* As = (bf16_t*)smem;
  bf16_t* Bs = (bf16_t*)(smem + 24576);
  bf16_t* tile = (bf16_t*)smem;

  int cz = blockIdx.z;
  const bf16_t* Ab = A + cz * zA + (long long)blockIdx.x * 128 * lda;
  const bf16_t* Bb = B + cz * zB + (long long)blockIdx.y * 64 * ldb;

  int t = threadIdx.x, wid = t >> 6, lane = t & 63;
  int wr = wid >> 1, wc = wid & 1;
  f32x4 acc[4][2] = {};
  int frow = lane & 15;
  int fk_sw = (((lane >> 4) ^ ((frow >> 1) & 3)) << 3);
  int srow = t >> 2;
  int scol_sw = (((t & 3) ^ ((t >> 3) & 3)) << 3);
  int nt = K >> 5;

  auto STAGE = [&](int TT, int BUF) {
    long long kko = (long long)TT * 32 + scol_sw;
    const bf16_t* ga0 = Ab + (long long)srow * lda + kko;
    const bf16_t* ga1 = Ab + (long long)(64 + srow) * lda + kko;
    const bf16_t* gb0 = Bb + (long long)srow * ldb + kko;
    char* la = smem + BUF * 8192 + wid * 1024;
    char* lb = smem + 24576 + BUF * 4096 + wid * 1024;
    __builtin_amdgcn_global_load_lds((AS1 void*)ga0, (AS3 void*)la, 16, 0, 0);
    __builtin_amdgcn_global_load_lds((AS1 void*)ga1, (AS3 void*)(la + 4096), 16, 0, 0);
    __builtin_amdgcn_global_load_lds((AS1 void*)gb0, (AS3 void*)lb, 16, 0, 0);
  };
  auto COMPUTE = [&](int BUF) {
    bf16x8 af[4], bfr[2];
#pragma unroll
    for (int m = 0; m < 4; ++m)
      af[m] = *(const bf16x8*)&As[BUF * 4096 + (wr * 64 + m * 16 + frow) * 32 + fk_sw];
#pragma unroll
    for (int n = 0; n < 2; ++n)
      bfr[n] = *(const bf16x8*)&Bs[BUF * 2048 + (wc * 32 + n * 16 + frow) * 32 + fk_sw];
#pragma unroll
    for (int m = 0; m < 4; ++m)
#pragma unroll
      for (int n = 0; n < 2; ++n)
        acc[m][n] = __builtin_amdgcn_mfma_f32_16x16x32_bf16(af[m], bfr[n], acc[m][n], 0, 0, 0);
  };

  STAGE(0, 0); STAGE(1, 1); STAGE(2, 2);
  int slot = 0;
  for (int tt = 0; tt < nt; ++tt) {
    int rem = nt - 1 - tt;
    if (rem >= 2)      asm volatile("s_waitcnt vmcnt(6)" ::: "memory");
    else if (rem == 1) asm volatile("s_waitcnt vmcnt(3)" ::: "memory");
    else               asm volatile("s_waitcnt vmcnt(0)" ::: "memory");
    __builtin_amdgcn_s_barrier();
    __builtin_amdgcn_sched_barrier(0);
    COMPUTE(slot);
    __builtin_amdgcn_s_barrier();
    if (tt + 3 < nt) STAGE(tt + 3, slot);
    slot = (slot == 2) ? 0 : slot + 1;
  }
  __builtin_amdgcn_sched_barrier(0);

  int rl0 = wr * 64 + ((lane >> 4) << 2);
  int cl0 = wc * 32 + (lane & 15);
  int r0 = blockIdx.x * 128 + rl0;
  int c0 = blockIdx.y * 64 + cl0;

  if constexpr (EP == EP_BF16O) {
    bf16_t* Cb = (bf16_t*)Cv + cz * zC;
#pragma unroll
    for (int m = 0; m < 4; ++m)
#pragma unroll
      for (int n = 0; n < 2; ++n)
#pragma unroll
        for (int j = 0; j < 4; ++j)
          Cb[(long long)(r0 + m * 16 + j) * N + c0 + n * 16] = (bf16_t)acc[m][n][j];
  } else if constexpr (EP == EP_XWDT) {
    float* Cb = (float*)Cv;
#pragma unroll
    for (int m = 0; m < 4; ++m)
#pragma unroll
      for (int n = 0; n < 2; ++n)
#pragma unroll
        for (int j = 0; j < 4; ++j) {
          float v = acc[m][n][j];
          Cb[(long long)(r0 + m * 16 + j) * N + c0 + n * 16] = v;
          tile[(rl0 + m * 16 + j) * 65 + cl0 + n * 16] = (bf16_t)v;
        }
    __syncthreads();
    int nl = t >> 5, rl = (t & 31) * 4;
#pragma unroll
    for (int vv = 0; vv < 8; ++vv) {
      int n_l = nl + vv * 8;
      bf16x4 v4;
      v4[0] = tile[(rl + 0) * 65 + n_l]; v4[1] = tile[(rl + 1) * 65 + n_l];
      v4[2] = tile[(rl + 2) * 65 + n_l]; v4[3] = tile[(rl + 3) * 65 + n_l];
      int i0 = blockIdx.x * 128 + rl;
      long long row = (long long)(blockIdx.y * 64 + n_l) * NN + i0;
#pragma unroll
      for (int c = 0; c < 2; ++c) {
        float4 dv = *(const float4*)&aux2[c * NN + i0];  // disv
        bf16x4 o;
        o[0] = (bf16_t)((float)v4[0] * dv.x); o[1] = (bf16_t)((float)v4[1] * dv.y);
        o[2] = (bf16_t)((float)v4[2] * dv.z); o[3] = (bf16_t)((float)v4[3] * dv.w);
        *(bf16x4*)&aux3[(long long)c * WOUT * NN + row] = o;
      }
    }
  } else if constexpr (EP == EP_GCN) {
    bf16_t* Cb = (bf16_t*)Cv;
    const float* XWp = aux1;
    const float* csp = aux2 + cz * NN;
    const float* dnp = aux2 + CC * NN + cz * NN;
    const float* mdp = aux2 + 2 * CC * NN + cz * NN;
    float bj[2];
#pragma unroll
    for (int n = 0; n < 2; ++n) bj[n] = aux4[c0 + n * 16];
#pragma unroll
    for (int m = 0; m < 4; ++m)
#pragma unroll
      for (int j = 0; j < 4; ++j) {
        int r = r0 + m * 16 + j;
        float csv = csp[r], dnv = dnp[r], mdv = mdp[r];
        float mdd = mdv * dnv, d2 = dnv * dnv;
#pragma unroll
        for (int n = 0; n < 2; ++n) {
          float xw = XWp[(long long)r * WOUT + c0 + n * 16];
          float v = fmaxf(csv * (acc[m][n][j] - mdd * xw) + d2 * xw + bj[n], 0.f);
          Cb[(long long)r * (CC * WOUT) + cz * WOUT + c0 + n * 16] = (bf16_t)v;
        }
      }
  } else if constexpr (EP == EP_BRELU) {
    bf16_t* Cb = (bf16_t*)Cv;
    float bj[2];
#pragma unroll
    for (int n = 0; n < 2; ++n) bj[n] = aux1[c0 + n * 16];
#pragma unroll
    for (int m = 0; m < 4; ++m)
#pragma unroll
      for (int n = 0; n < 2; ++n)
#pragma unroll
        for (int j = 0; j < 4; ++j)
          Cb[(long long)(r0 + m * 16 + j) * N + c0 + n * 16] =
              (bf16_t)fmaxf(acc[m][n][j] + bj[n], 0.f);
  } else { // EP_BF32
    float* Cb = (float*)Cv;
    float bj[2];
#pragma unroll
    for (int n = 0; n < 2; ++n) bj[n] = aux1[c0 + n * 16];
#pragma unroll
    for (int m = 0; m < 4; ++m)
#pragma unroll
      for (int n = 0; n < 2; ++n)
#pragma unroll
        for (int j = 0; j < 4; ++j)
          Cb[(long long)(r0 + m * 16 + j) * N + c0 + n * 16] = acc[m][n][j] + bj[n];
  }
}

// ---------------- launch ----------------

extern "C" void kernel_launch(void* const* d_in, const int* in_sizes, int n_in,
                              void* d_out, int out_size, void* d_ws, size_t ws_size,
                              hipStream_t stream) {
  const float* A    = (const float*)d_in[0];
  const float* X    = (const float*)d_in[1];
  const float* w0a  = (const float*)d_in[2];
  const float* w0b  = (const float*)d_in[3];
  const float* w1   = (const float*)d_in[4];
  const float* gcnw = (const float*)d_in[5];
  const float* gcnb = (const float*)d_in[6];
  const float* l1w  = (const float*)d_in[7];
  const float* l1b  = (const float*)d_in[8];
  const float* l2w  = (const float*)d_in[9];
  const float* l2b  = (const float*)d_in[10];
  float* out = (float*)d_out;

  char* p = (char*)d_ws;
  auto carve = [&](size_t bytes) -> char* {
    char* r = p; p += (bytes + 255) & ~(size_t)255; return r;
  };
  float*  svec  = (float*)carve((size_t)CC * NN * 4);
  float*  dinv1 = (float*)carve((size_t)CC * NN * 4);
  float*  m1    = (float*)carve((size_t)CC * NN * 4);
  float*  scal  = (float*)carve((size_t)3 * CC * NN * 4);  // cscal | disv | Mdiag
  float*  part  = (float*)carve((size_t)CC * 32 * NN * 4);
  bf16_t* S1    = (bf16_t*)carve((size_t)CC * N2 * 2);  // Ha -> {XWdT, Yt}
  bf16_t* HbT   = (bf16_t*)carve((size_t)CC * N2 * 2);
  bf16_t* Hb2T  = (bf16_t*)carve((size_t)CC * N2 * 2);
  bf16_t* Hn    = (bf16_t*)carve((size_t)CC * N2 * 2);
  bf16_t* HnT   = (bf16_t*)carve((size_t)CC * N2 * 2);
  bf16_t* Xb    = (bf16_t*)carve((size_t)NN * WIN * 2);
  bf16_t* gwT   = (bf16_t*)carve((size_t)WOUT * WIN * 2);
  bf16_t* l1wb  = (bf16_t*)carve((size_t)WOUT * CC * WOUT * 2);
  bf16_t* l2wb  = (bf16_t*)carve((size_t)WOUT * WOUT * 2);
  float*  XW    = (float*)carve((size_t)NN * WOUT * 4);
  bf16_t* Xcat  = (bf16_t*)carve((size_t)NN * CC * WOUT * 2);
  bf16_t* hb    = (bf16_t*)carve((size_t)NN * WOUT * 2);

  bf16_t* Ha = S1;
  bf16_t* XWdT = (bf16_t*)((char*)S1);                 // 2 MB
  bf16_t* Yt   = (bf16_t*)((char*)S1 + (2LL << 20));   // 2 MB
  float*  disv = scal + CC * NN;

  // combine (+merged prep)
  k_combine<<<1664, 256, 0, stream>>>(A, w0a, w0b, w1, Ha, HbT, Hb2T, part,
                                      X, l1w, l2w, gcnw, Xb, l1wb, l2wb, gwT);
  k_s_finish<<<16, 256, 0, stream>>>(part, svec);

  // layer 0: analytic degrees; GEMM1 (barrier-free wave-private) fused normalize -> Hn + HnT
  k_deg<false><<<dim3(512, 2), 256, 0, stream>>>(svec, Ha, HbT, dinv1, m1, nullptr);
  k_gemmL<<<dim3(16, 16, 2), 256, 0, stream>>>(Ha, HbT, Hn, HnT, dinv1);

  // layer 1 scalars (packed: cscal | disv | Mdiag)
  k_deg<true><<<dim3(512, 2), 256, 0, stream>>>(m1, Hn, Hb2T,
                                                scal, scal + CC * NN, scal + 2 * CC * NN);

  // GCN via associativity: XW (+fused disv-scaled transpose -> XWdT both channels);
  // Yt = XWdT @ HnT^T; Xcat = gcn-epilogue(Hb2T @ Yt^T)
  k_gemm<EP_XWDT><<<dim3(16, 4, 1), 256, 0, stream>>>(
      Xb, gwT, XW, nullptr, disv, XWdT, nullptr, WOUT, WIN, WIN, WIN, 0, 0, 0);
  k_gemm<EP_BF16O><<<dim3(2, 32, 2), 256, 0, stream>>>(
      XWdT, HnT, Yt, nullptr, nullptr, nullptr, nullptr, NN, NN, NN, NN,
      (long long)WOUT * NN, N2, (long long)WOUT * NN);
  k_gemm<EP_GCN><<<dim3(16, 4, 2), 256, 0, stream>>>(
      Hb2T, Yt, Xcat, XW, scal, nullptr, gcnb, WOUT, NN, NN, NN,
      N2, (long long)WOUT * NN, 0);

  // MLP with fused bias(+relu)
  k_gemm<EP_BRELU><<<dim3(16, 4, 1), 256, 0, stream>>>(
      Xcat, l1wb, hb, l1b, nullptr, nullptr, nullptr, WOUT, CC * WOUT, CC * WOUT, CC * WOUT, 0, 0, 0);
  k_gemm<EP_BF32><<<dim3(16, 4, 1), 256, 0, stream>>>(
      hb, l2wb, out, l2b, nullptr, nullptr, nullptr, WOUT, WOUT, WOUT, WOUT, 0, 0, 0);
}

// Round 12
// 144.251 us; speedup vs baseline: 1.1430x; 1.1430x over previous
//
#include <hip/hip_runtime.h>
#include <cstdint>
#include <cstddef>

#define NN   2048
#define N2   (2048LL*2048LL)
#define CC   2
#define EE   5
#define WIN  512
#define WOUT 256

typedef __bf16 bf16_t;
typedef __attribute__((ext_vector_type(8))) __bf16 bf16x8;
typedef __attribute__((ext_vector_type(4))) __bf16 bf16x4;
typedef __attribute__((ext_vector_type(4))) float  f32x4;

#define AS1 __attribute__((address_space(1)))
#define AS3 __attribute__((address_space(3)))

// ---------------- combine (+merged prep): single A pass; Hb via LDS, Hb2 in registers ----------------
// grid: 1024 combine blocks + 640 prep blocks (1D, 1664)

__global__ void k_combine(const float* __restrict__ A,
                          const float* __restrict__ w0a, const float* __restrict__ w0b,
                          const float* __restrict__ w1,
                          bf16_t* __restrict__ Ha, bf16_t* __restrict__ HbT,
                          bf16_t* __restrict__ Hb2T, float* __restrict__ part,
                          const float* __restrict__ X, const float* __restrict__ l1w,
                          const float* __restrict__ l2w, const float* __restrict__ gcnw,
                          bf16_t* __restrict__ Xb, bf16_t* __restrict__ l1wb,
                          bf16_t* __restrict__ l2wb, bf16_t* __restrict__ gwT) {
  __shared__ bf16_t tl[2][64][65];   // 16.6 KB
  __shared__ float cs[2][4][64];     // 2 KB (per-wave colsum partials)
  int bid = blockIdx.x;
  int t = threadIdx.x;

  if (bid >= 1024) {
    // ---- prep path ----
    int bid2 = bid - 1024;
    if (bid2 < 608) {
      int i = bid2 * 256 + t;
      const float* src; bf16_t* dst; int off;
      if (i < 131072)      { src = X;   dst = Xb;   off = i; }
      else if (i < 147456) { src = l1w; dst = l1wb; off = i - 131072; }
      else                 { src = l2w; dst = l2wb; off = i - 147456; }
      float4 a = ((const float4*)src)[off * 2];
      float4 b = ((const float4*)src)[off * 2 + 1];
      bf16x8 o;
      o[0] = (bf16_t)a.x; o[1] = (bf16_t)a.y; o[2] = (bf16_t)a.z; o[3] = (bf16_t)a.w;
      o[4] = (bf16_t)b.x; o[5] = (bf16_t)b.y; o[6] = (bf16_t)b.z; o[7] = (bf16_t)b.w;
      ((bf16x8*)dst)[off] = o;
    } else {
      int b2 = bid2 - 608;             // 0..31
      int m0 = (b2 & 7) * 64, n0 = (b2 >> 3) * 64;
      int tr = t >> 4, tc = (t & 15) << 2;
      bf16_t (*tile)[65] = (bf16_t (*)[65])&tl[0][0][0];
#pragma unroll
      for (int v = 0; v < 4; ++v) {
        int r = tr + v * 16;
        float4 d = *(const float4*)&gcnw[(long long)(m0 + r) * WOUT + n0 + tc];
        tile[r][tc + 0] = (bf16_t)d.x; tile[r][tc + 1] = (bf16_t)d.y;
        tile[r][tc + 2] = (bf16_t)d.z; tile[r][tc + 3] = (bf16_t)d.w;
      }
      __syncthreads();
#pragma unroll
      for (int v = 0; v < 4; ++v) {
        int r = tr + v * 16;
        bf16x4 o;
        o[0] = tile[tc + 0][r]; o[1] = tile[tc + 1][r];
        o[2] = tile[tc + 2][r]; o[3] = tile[tc + 3][r];
        *(bf16x4*)&gwT[(long long)(n0 + r) * WIN + m0 + tc] = o;
      }
    }
    return;
  }

  // ---- combine path ----
  float f[3][2][5];
  {
    const float* wp[3] = {w0a, w0b, w1};
#pragma unroll
    for (int w = 0; w < 3; ++w)
#pragma unroll
      for (int c = 0; c < 2; ++c) {
        float x[5], m = -1e30f, s = 0.f;
#pragma unroll
        for (int e = 0; e < 5; ++e) { x[e] = wp[w][c * 5 + e]; m = fmaxf(m, x[e]); }
#pragma unroll
        for (int e = 0; e < 5; ++e) { x[e] = expf(x[e] - m); s += x[e]; }
#pragma unroll
        for (int e = 0; e < 5; ++e) f[w][c][e] = x[e] / s;
      }
  }
  int i0 = (bid >> 5) * 64, j0 = (bid & 31) * 64;
  int tr = t >> 4, tc = (t & 15) << 2;
  int lane = t & 63, wid = t >> 6;
  float cs0[4] = {0, 0, 0, 0}, cs1[4] = {0, 0, 0, 0};
  bf16x4 hb2a[4], hb2b[4];

#pragma unroll
  for (int v = 0; v < 4; ++v) {
    int lr = tr + v * 16;
    long long gi = i0 + lr;
    const float* base = A + gi * (long long)NN + j0 + tc;
    float av[5][4];
#pragma unroll
    for (int e = 0; e < 5; ++e) {
      float4 q = *(const float4*)(base + (long long)e * N2);
      av[e][0] = q.x; av[e][1] = q.y; av[e][2] = q.z; av[e][3] = q.w;
    }
    bf16x4 ha0, ha1;
#pragma unroll
    for (int x = 0; x < 4; ++x) {
      float s0 = 0.f, s1 = 0.f, s2 = 0.f, s3 = 0.f, s4 = 0.f, s5 = 0.f;
#pragma unroll
      for (int e = 0; e < 5; ++e) {
        float u = av[e][x];
        s0 += f[0][0][e] * u; s1 += f[0][1][e] * u;
        s2 += f[1][0][e] * u; s3 += f[1][1][e] * u;
        s4 += f[2][0][e] * u; s5 += f[2][1][e] * u;
      }
      ha0[x] = (bf16_t)s0; cs0[x] += (float)ha0[x];
      ha1[x] = (bf16_t)s1; cs1[x] += (float)ha1[x];
      tl[0][lr][tc + x] = (bf16_t)s2; tl[1][lr][tc + x] = (bf16_t)s3;
      hb2a[v][x] = (bf16_t)s4; hb2b[v][x] = (bf16_t)s5;
    }
    *(bf16x4*)&Ha[0 * N2 + gi * NN + j0 + tc] = ha0;
    *(bf16x4*)&Ha[1 * N2 + gi * NN + j0 + tc] = ha1;
  }
  // intra-wave reduce over lane>>4 (4 of the 16 row-groups per wave), then LDS
#pragma unroll
  for (int x = 0; x < 4; ++x) {
    float a0 = cs0[x], a1 = cs1[x];
    a0 += __shfl_xor(a0, 16, 64); a0 += __shfl_xor(a0, 32, 64);
    a1 += __shfl_xor(a1, 16, 64); a1 += __shfl_xor(a1, 32, 64);
    if ((lane >> 4) == 0) {
      cs[0][wid][(lane & 15) * 4 + x] = a0;
      cs[1][wid][(lane & 15) * 4 + x] = a1;
    }
  }
  __syncthreads();

#pragma unroll
  for (int v = 0; v < 4; ++v) {
    int lr = tr + v * 16;
#pragma unroll
    for (int ch = 0; ch < 2; ++ch) {
      bf16x4 o;
      o[0] = tl[ch][tc + 0][lr]; o[1] = tl[ch][tc + 1][lr];
      o[2] = tl[ch][tc + 2][lr]; o[3] = tl[ch][tc + 3][lr];
      *(bf16x4*)&HbT[(long long)ch * N2 + (long long)(j0 + lr) * NN + i0 + tc] = o;
    }
  }
  if (t < 128) {
    int ch = t >> 6, col = t & 63;
    float s = cs[ch][0][col] + cs[ch][1][col] + cs[ch][2][col] + cs[ch][3][col];
    part[((long long)ch * 32 + (bid >> 5)) * NN + j0 + col] = s;
  }
  __syncthreads();

#pragma unroll
  for (int v = 0; v < 4; ++v) {
    int lr = tr + v * 16;
#pragma unroll
    for (int x = 0; x < 4; ++x) {
      tl[0][lr][tc + x] = hb2a[v][x];
      tl[1][lr][tc + x] = hb2b[v][x];
    }
  }
  __syncthreads();

#pragma unroll
  for (int v = 0; v < 4; ++v) {
    int lr = tr + v * 16;
#pragma unroll
    for (int ch = 0; ch < 2; ++ch) {
      bf16x4 o;
      o[0] = tl[ch][tc + 0][lr]; o[1] = tl[ch][tc + 1][lr];
      o[2] = tl[ch][tc + 2][lr]; o[3] = tl[ch][tc + 3][lr];
      *(bf16x4*)&Hb2T[(long long)ch * N2 + (long long)(j0 + lr) * NN + i0 + tc] = o;
    }
  }
}

__global__ void k_s_finish(const float* __restrict__ part, float* __restrict__ s) {
  int idx = blockIdx.x * 256 + threadIdx.x;
  int c = idx >> 11, k = idx & 2047;
  float acc = 0.f;
#pragma unroll
  for (int ib = 0; ib < 32; ++ib) acc += part[((long long)c * 32 + ib) * NN + k];
  s[idx] = acc;
}

// deg[c][j] = sum_k (svec[k] - A[j,k])*BT[j,k];  Mdiag[c][j] = sum_k A[j,k]*BT[j,k]
template<bool EMIT_DIS>
__global__ void k_deg(const float* __restrict__ svec, const bf16_t* __restrict__ Arows,
                      const bf16_t* __restrict__ BT,
                      float* __restrict__ out1, float* __restrict__ out2,
                      float* __restrict__ out3) {
  int c = blockIdx.y;
  int j = blockIdx.x * 4 + (threadIdx.x >> 6);
  int lane = threadIdx.x & 63;
  const bf16_t* a = Arows + (long long)c * N2 + (long long)j * NN;
  const bf16_t* b = BT + (long long)c * N2 + (long long)j * NN;
  const float* s = svec + c * NN;
  float acc_s = 0.f, acc_a = 0.f;
#pragma unroll
  for (int it = 0; it < 4; ++it) {
    int k0 = (lane + it * 64) * 8;
    bf16x8 av = *(const bf16x8*)(a + k0);
    bf16x8 bv = *(const bf16x8*)(b + k0);
    float4 s0 = *(const float4*)(s + k0);
    float4 s1 = *(const float4*)(s + k0 + 4);
    float sv[8] = {s0.x, s0.y, s0.z, s0.w, s1.x, s1.y, s1.z, s1.w};
#pragma unroll
    for (int x = 0; x < 8; ++x) {
      float bx = (float)bv[x];
      acc_s += sv[x] * bx;
      acc_a += (float)av[x] * bx;
    }
  }
#pragma unroll
  for (int o = 32; o > 0; o >>= 1) {
    acc_s += __shfl_xor(acc_s, o, 64);
    acc_a += __shfl_xor(acc_a, o, 64);
  }
  if (lane == 0) {
    float deg = acc_s - acc_a;
    bool nz = (deg != 0.f);
    if (!EMIT_DIS) {
      out1[c * NN + j] = nz ? 1.f / deg : 0.f;
      out2[c * NN + j] = nz ? 1.f : 0.f;
    } else {
      float dis = nz ? 0.70710678118654752f : 1.f;
      out1[c * NN + j] = nz ? dis / deg : 0.f;     // cscal
      out2[c * NN + j] = dis;                      // disv
      out3[c * NN + j] = acc_a;                    // Mdiag
    }
  }
}

// ---------------- GEMM1: 128x128 tile, BK=64 slots (2x BK32 sub-tiles), ring-2 (R8 config) ----------------

__global__ __launch_bounds__(256)
void k_gemmL(const bf16_t* __restrict__ A, const bf16_t* __restrict__ B,
             bf16_t* __restrict__ Hn, bf16_t* __restrict__ HnT,
             const float* __restrict__ dinv) {
  __shared__ __align__(16) char smem[65536];
  bf16_t* As = (bf16_t*)smem;
  bf16_t* Bs = (bf16_t*)(smem + 32768);
  bf16_t* tile = (bf16_t*)smem;

  int cz = blockIdx.z;
  const bf16_t* Ab = A + cz * N2 + (long long)blockIdx.x * 128 * NN;
  const bf16_t* Bb = B + cz * N2 + (long long)blockIdx.y * 128 * NN;

  int t = threadIdx.x, wid = t >> 6, lane = t & 63;
  int wr = wid >> 1, wc = wid & 1;
  f32x4 acc[4][4] = {};
  int frow = lane & 15;
  int fk_sw = (((lane >> 4) ^ ((frow >> 1) & 3)) << 3);
  int srow = t >> 2;
  int scol_sw = (((t & 3) ^ ((t >> 3) & 3)) << 3);

  auto STAGE = [&](int TT, int BUF) {
#pragma unroll
    for (int s = 0; s < 2; ++s) {
      long long kko = (long long)TT * 64 + s * 32 + scol_sw;
      const bf16_t* ga0 = Ab + (long long)srow * NN + kko;
      const bf16_t* gb0 = Bb + (long long)srow * NN + kko;
      char* la = smem + BUF * 16384 + s * 8192 + wid * 1024;
      char* lb = smem + 32768 + BUF * 16384 + s * 8192 + wid * 1024;
      __builtin_amdgcn_global_load_lds((AS1 void*)ga0, (AS3 void*)la, 16, 0, 0);
      __builtin_amdgcn_global_load_lds((AS1 void*)(ga0 + 64LL * NN), (AS3 void*)(la + 4096), 16, 0, 0);
      __builtin_amdgcn_global_load_lds((AS1 void*)gb0, (AS3 void*)lb, 16, 0, 0);
      __builtin_amdgcn_global_load_lds((AS1 void*)(gb0 + 64LL * NN), (AS3 void*)(lb + 4096), 16, 0, 0);
    }
  };
  auto COMPUTE = [&](int BUF) {
#pragma unroll
    for (int ks = 0; ks < 2; ++ks) {
      bf16x8 af[4], bfr[4];
#pragma unroll
      for (int m = 0; m < 4; ++m)
        af[m] = *(const bf16x8*)&As[BUF * 8192 + ks * 4096 + (wr * 64 + m * 16 + frow) * 32 + fk_sw];
#pragma unroll
      for (int n = 0; n < 4; ++n)
        bfr[n] = *(const bf16x8*)&Bs[BUF * 8192 + ks * 4096 + (wc * 64 + n * 16 + frow) * 32 + fk_sw];
      __builtin_amdgcn_s_setprio(1);
#pragma unroll
      for (int m = 0; m < 4; ++m)
#pragma unroll
        for (int n = 0; n < 4; ++n)
          acc[m][n] = __builtin_amdgcn_mfma_f32_16x16x32_bf16(af[m], bfr[n], acc[m][n], 0, 0, 0);
      __builtin_amdgcn_s_setprio(0);
    }
  };

  const int nt = 32;  // K/64
  STAGE(0, 0); STAGE(1, 1);
  for (int tt = 0; tt < nt; ++tt) {
    if (tt < nt - 1) asm volatile("s_waitcnt vmcnt(8)" ::: "memory");
    else             asm volatile("s_waitcnt vmcnt(0)" ::: "memory");
    __builtin_amdgcn_s_barrier();
    __builtin_amdgcn_sched_barrier(0);
    COMPUTE(tt & 1);
    __builtin_amdgcn_s_barrier();
    if (tt + 2 < nt) STAGE(tt + 2, tt & 1);
  }
  __builtin_amdgcn_sched_barrier(0);

  int rl0 = wr * 64 + ((lane >> 4) << 2);
  int cl0 = wc * 64 + (lane & 15);
  int r0 = blockIdx.x * 128 + rl0;
  int c0 = blockIdx.y * 128 + cl0;

  bf16_t* Cb = Hn + cz * N2;
  bf16_t* Ct = HnT + cz * N2;
  float dj[4];
#pragma unroll
  for (int n = 0; n < 4; ++n) dj[n] = dinv[cz * NN + c0 + n * 16];
#pragma unroll
  for (int m = 0; m < 4; ++m)
#pragma unroll
    for (int n = 0; n < 4; ++n)
#pragma unroll
      for (int j = 0; j < 4; ++j) {
        int r = r0 + m * 16 + j, col = c0 + n * 16;
        float v = (r == col) ? 0.f : acc[m][n][j] * dj[n];
        Cb[(long long)r * NN + col] = (bf16_t)v;
        tile[(rl0 + m * 16 + j) * 130 + cl0 + n * 16] = (bf16_t)v;
      }
  __syncthreads();
  int nl = t >> 5, rl = (t & 31) * 4;
#pragma unroll
  for (int vv = 0; vv < 16; ++vv) {
    int n_l = nl + vv * 8;
    bf16x4 o;
    o[0] = tile[(rl + 0) * 130 + n_l]; o[1] = tile[(rl + 1) * 130 + n_l];
    o[2] = tile[(rl + 2) * 130 + n_l]; o[3] = tile[(rl + 3) * 130 + n_l];
    *(bf16x4*)&Ct[(long long)(blockIdx.y * 128 + n_l) * NN + blockIdx.x * 128 + rl] = o;
  }
}

// ---------------- bf16 GEMM, 128x64 tile, ring-3, counted vmcnt, swizzle, fused epilogues ----------------

enum { EP_BRELU = 3, EP_BF32 = 4, EP_BF16O = 7, EP_XWDT = 8, EP_GCN = 9 };

template<int EP>
__global__ __launch_bounds__(256)
void k_gemm(const bf16_t* __restrict__ A, const bf16_t* __restrict__ B,
            void* __restrict__ Cv,
            const float* __restrict__ aux1, const float* __restrict__ aux2,
            bf16_t* __restrict__ aux3, const float* __restrict__ aux4,
            int N, int K, int lda, int ldb,
            long long zA, long long zB, long long zC) {
  __shared__ __align__(16) char smem[36864];
  bf16_t* As = (bf16_t*)smem;
  bf16_t* Bs = (bf16_t*)(smem + 24576);
  bf16_t* tile = (bf16_t*)smem;

  int cz = blockIdx.z;
  const bf16_t* Ab = A + cz * zA + (long long)blockIdx.x * 128 * lda;
  const bf16_t* Bb = B + cz * zB + (long long)blockIdx.y * 64 * ldb;

  int t = threadIdx.x, wid = t >> 6, lane = t & 63;
  int wr = wid >> 1, wc = wid & 1;
  f32x4 acc[4][2] = {};
  int frow = lane & 15;
  int fk_sw = (((lane >> 4) ^ ((frow >> 1) & 3)) << 3);
  int srow = t >> 2;
  int scol_sw = (((t & 3) ^ ((t >> 3) & 3)) << 3);
  int nt = K >> 5;

  auto STAGE = [&](int TT, int BUF) {
    long long kko = (long long)TT * 32 + scol_sw;
    const bf16_t* ga0 = Ab + (long long)srow * lda + kko;
    const bf16_t* ga1 = Ab + (long long)(64 + srow) * lda + kko;
    const bf16_t* gb0 = Bb + (long long)srow * ldb + kko;
    char* la = smem + BUF * 8192 + wid * 1024;
    char* lb = smem + 24576 + BUF * 4096 + wid * 1024;
    __builtin_amdgcn_global_load_lds((AS1 void*)ga0, (AS3 void*)la, 16, 0, 0);
    __builtin_amdgcn_global_load_lds((AS1 void*)ga1, (AS3 void*)(la + 4096), 16, 0, 0);
    __builtin_amdgcn_global_load_lds((AS1 void*)gb0, (AS3 void*)lb, 16, 0, 0);
  };
  auto COMPUTE = [&](int BUF) {
    bf16x8 af[4], bfr[2];
#pragma unroll
    for (int m = 0; m < 4; ++m)
      af[m] = *(const bf16x8*)&As[BUF * 4096 + (wr * 64 + m * 16 + frow) * 32 + fk_sw];
#pragma unroll
    for (int n = 0; n < 2; ++n)
      bfr[n] = *(const bf16x8*)&Bs[BUF * 2048 + (wc * 32 + n * 16 + frow) * 32 + fk_sw];
#pragma unroll
    for (int m = 0; m < 4; ++m)
#pragma unroll
      for (int n = 0; n < 2; ++n)
        acc[m][n] = __builtin_amdgcn_mfma_f32_16x16x32_bf16(af[m], bfr[n], acc[m][n], 0, 0, 0);
  };

  STAGE(0, 0); STAGE(1, 1); STAGE(2, 2);
  int slot = 0;
  for (int tt = 0; tt < nt; ++tt) {
    int rem = nt - 1 - tt;
    if (rem >= 2)      asm volatile("s_waitcnt vmcnt(6)" ::: "memory");
    else if (rem == 1) asm volatile("s_waitcnt vmcnt(3)" ::: "memory");
    else               asm volatile("s_waitcnt vmcnt(0)" ::: "memory");
    __builtin_amdgcn_s_barrier();
    __builtin_amdgcn_sched_barrier(0);
    COMPUTE(slot);
    __builtin_amdgcn_s_barrier();
    if (tt + 3 < nt) STAGE(tt + 3, slot);
    slot = (slot == 2) ? 0 : slot + 1;
  }
  __builtin_amdgcn_sched_barrier(0);

  int rl0 = wr * 64 + ((lane >> 4) << 2);
  int cl0 = wc * 32 + (lane & 15);
  int r0 = blockIdx.x * 128 + rl0;
  int c0 = blockIdx.y * 64 + cl0;

  if constexpr (EP == EP_BF16O) {
    bf16_t* Cb = (bf16_t*)Cv + cz * zC;
#pragma unroll
    for (int m = 0; m < 4; ++m)
#pragma unroll
      for (int n = 0; n < 2; ++n)
#pragma unroll
        for (int j = 0; j < 4; ++j)
          Cb[(long long)(r0 + m * 16 + j) * N + c0 + n * 16] = (bf16_t)acc[m][n][j];
  } else if constexpr (EP == EP_XWDT) {
    float* Cb = (float*)Cv;
#pragma unroll
    for (int m = 0; m < 4; ++m)
#pragma unroll
      for (int n = 0; n < 2; ++n)
#pragma unroll
        for (int j = 0; j < 4; ++j) {
          float v = acc[m][n][j];
          Cb[(long long)(r0 + m * 16 + j) * N + c0 + n * 16] = v;
          tile[(rl0 + m * 16 + j) * 65 + cl0 + n * 16] = (bf16_t)v;
        }
    __syncthreads();
    int nl = t >> 5, rl = (t & 31) * 4;
#pragma unroll
    for (int vv = 0; vv < 8; ++vv) {
      int n_l = nl + vv * 8;
      bf16x4 v4;
      v4[0] = tile[(rl + 0) * 65 + n_l]; v4[1] = tile[(rl + 1) * 65 + n_l];
      v4[2] = tile[(rl + 2) * 65 + n_l]; v4[3] = tile[(rl + 3) * 65 + n_l];
      int i0 = blockIdx.x * 128 + rl;
      long long row = (long long)(blockIdx.y * 64 + n_l) * NN + i0;
#pragma unroll
      for (int c = 0; c < 2; ++c) {
        float4 dv = *(const float4*)&aux2[c * NN + i0];  // disv
        bf16x4 o;
        o[0] = (bf16_t)((float)v4[0] * dv.x); o[1] = (bf16_t)((float)v4[1] * dv.y);
        o[2] = (bf16_t)((float)v4[2] * dv.z); o[3] = (bf16_t)((float)v4[3] * dv.w);
        *(bf16x4*)&aux3[(long long)c * WOUT * NN + row] = o;
      }
    }
  } else if constexpr (EP == EP_GCN) {
    bf16_t* Cb = (bf16_t*)Cv;
    const float* XWp = aux1;
    const float* csp = aux2 + cz * NN;
    const float* dnp = aux2 + CC * NN + cz * NN;
    const float* mdp = aux2 + 2 * CC * NN + cz * NN;
    float bj[2];
#pragma unroll
    for (int n = 0; n < 2; ++n) bj[n] = aux4[c0 + n * 16];
#pragma unroll
    for (int m = 0; m < 4; ++m)
#pragma unroll
      for (int j = 0; j < 4; ++j) {
        int r = r0 + m * 16 + j;
        float csv = csp[r], dnv = dnp[r], mdv = mdp[r];
        float mdd = mdv * dnv, d2 = dnv * dnv;
#pragma unroll
        for (int n = 0; n < 2; ++n) {
          float xw = XWp[(long long)r * WOUT + c0 + n * 16];
          float v = fmaxf(csv * (acc[m][n][j] - mdd * xw) + d2 * xw + bj[n], 0.f);
          Cb[(long long)r * (CC * WOUT) + cz * WOUT + c0 + n * 16] = (bf16_t)v;
        }
      }
  } else if constexpr (EP == EP_BRELU) {
    bf16_t* Cb = (bf16_t*)Cv;
    float bj[2];
#pragma unroll
    for (int n = 0; n < 2; ++n) bj[n] = aux1[c0 + n * 16];
#pragma unroll
    for (int m = 0; m < 4; ++m)
#pragma unroll
      for (int n = 0; n < 2; ++n)
#pragma unroll
        for (int j = 0; j < 4; ++j)
          Cb[(long long)(r0 + m * 16 + j) * N + c0 + n * 16] =
              (bf16_t)fmaxf(acc[m][n][j] + bj[n], 0.f);
  } else { // EP_BF32
    float* Cb = (float*)Cv;
    float bj[2];
#pragma unroll
    for (int n = 0; n < 2; ++n) bj[n] = aux1[c0 + n * 16];
#pragma unroll
    for (int m = 0; m < 4; ++m)
#pragma unroll
      for (int n = 0; n < 2; ++n)
#pragma unroll
        for (int j = 0; j < 4; ++j)
          Cb[(long long)(r0 + m * 16 + j) * N + c0 + n * 16] = acc[m][n][j] + bj[n];
  }
}

// ---------------- launch ----------------

extern "C" void kernel_launch(void* const* d_in, const int* in_sizes, int n_in,
                              void* d_out, int out_size, void* d_ws, size_t ws_size,
                              hipStream_t stream) {
  const float* A    = (const float*)d_in[0];
  const float* X    = (const float*)d_in[1];
  const float* w0a  = (const float*)d_in[2];
  const float* w0b  = (const float*)d_in[3];
  const float* w1   = (const float*)d_in[4];
  const float* gcnw = (const float*)d_in[5];
  const float* gcnb = (const float*)d_in[6];
  const float* l1w  = (const float*)d_in[7];
  const float* l1b  = (const float*)d_in[8];
  const float* l2w  = (const float*)d_in[9];
  const float* l2b  = (const float*)d_in[10];
  float* out = (float*)d_out;

  char* p = (char*)d_ws;
  auto carve = [&](size_t bytes) -> char* {
    char* r = p; p += (bytes + 255) & ~(size_t)255; return r;
  };
  float*  svec  = (float*)carve((size_t)CC * NN * 4);
  float*  dinv1 = (float*)carve((size_t)CC * NN * 4);
  float*  m1    = (float*)carve((size_t)CC * NN * 4);
  float*  scal  = (float*)carve((size_t)3 * CC * NN * 4);  // cscal | disv | Mdiag
  float*  part  = (float*)carve((size_t)CC * 32 * NN * 4);
  bf16_t* S1    = (bf16_t*)carve((size_t)CC * N2 * 2);  // Ha -> {XWdT, Yt}
  bf16_t* HbT   = (bf16_t*)carve((size_t)CC * N2 * 2);
  bf16_t* Hb2T  = (bf16_t*)carve((size_t)CC * N2 * 2);
  bf16_t* Hn    = (bf16_t*)carve((size_t)CC * N2 * 2);
  bf16_t* HnT   = (bf16_t*)carve((size_t)CC * N2 * 2);
  bf16_t* Xb    = (bf16_t*)carve((size_t)NN * WIN * 2);
  bf16_t* gwT   = (bf16_t*)carve((size_t)WOUT * WIN * 2);
  bf16_t* l1wb  = (bf16_t*)carve((size_t)WOUT * CC * WOUT * 2);
  bf16_t* l2wb  = (bf16_t*)carve((size_t)WOUT * WOUT * 2);
  float*  XW    = (float*)carve((size_t)NN * WOUT * 4);
  bf16_t* Xcat  = (bf16_t*)carve((size_t)NN * CC * WOUT * 2);
  bf16_t* hb    = (bf16_t*)carve((size_t)NN * WOUT * 2);

  bf16_t* Ha = S1;
  bf16_t* XWdT = (bf16_t*)((char*)S1);                 // 2 MB
  bf16_t* Yt   = (bf16_t*)((char*)S1 + (2LL << 20));   // 2 MB
  float*  disv = scal + CC * NN;

  // combine (+merged prep)
  k_combine<<<1664, 256, 0, stream>>>(A, w0a, w0b, w1, Ha, HbT, Hb2T, part,
                                      X, l1w, l2w, gcnw, Xb, l1wb, l2wb, gwT);
  k_s_finish<<<16, 256, 0, stream>>>(part, svec);

  // layer 0: analytic degrees; GEMM1 (R8 config) fused normalize -> Hn + HnT
  k_deg<false><<<dim3(512, 2), 256, 0, stream>>>(svec, Ha, HbT, dinv1, m1, nullptr);
  k_gemmL<<<dim3(16, 16, 2), 256, 0, stream>>>(Ha, HbT, Hn, HnT, dinv1);

  // layer 1 scalars (packed: cscal | disv | Mdiag)
  k_deg<true><<<dim3(512, 2), 256, 0, stream>>>(m1, Hn, Hb2T,
                                                scal, scal + CC * NN, scal + 2 * CC * NN);

  // GCN via associativity: XW (+fused disv-scaled transpose -> XWdT both channels);
  // Yt = XWdT @ HnT^T; Xcat = gcn-epilogue(Hb2T @ Yt^T)
  k_gemm<EP_XWDT><<<dim3(16, 4, 1), 256, 0, stream>>>(
      Xb, gwT, XW, nullptr, disv, XWdT, nullptr, WOUT, WIN, WIN, WIN, 0, 0, 0);
  k_gemm<EP_BF16O><<<dim3(2, 32, 2), 256, 0, stream>>>(
      XWdT, HnT, Yt, nullptr, nullptr, nullptr, nullptr, NN, NN, NN, NN,
      (long long)WOUT * NN, N2, (long long)WOUT * NN);
  k_gemm<EP_GCN><<<dim3(16, 4, 2), 256, 0, stream>>>(
      Hb2T, Yt, Xcat, XW, scal, nullptr, gcnb, WOUT, NN, NN, NN,
      N2, (long long)WOUT * NN, 0);

  // MLP with fused bias(+relu)
  k_gemm<EP_BRELU><<<dim3(16, 4, 1), 256, 0, stream>>>(
      Xcat, l1wb, hb, l1b, nullptr, nullptr, nullptr, WOUT, CC * WOUT, CC * WOUT, CC * WOUT, 0, 0, 0);
  k_gemm<EP_BF32><<<dim3(16, 4, 1), 256, 0, stream>>>(
      hb, l2wb, out, l2b, nullptr, nullptr, nullptr, WOUT, WOUT, WOUT, WOUT, 0, 0, 0);
}

// Round 13
// 142.379 us; speedup vs baseline: 1.1580x; 1.0131x over previous
//
#include <hip/hip_runtime.h>
#include <cstdint>
#include <cstddef>

#define NN   2048
#define N2   (2048LL*2048LL)
#define CC   2
#define EE   5
#define WIN  512
#define WOUT 256

typedef __bf16 bf16_t;
typedef __attribute__((ext_vector_type(8))) __bf16 bf16x8;
typedef __attribute__((ext_vector_type(4))) __bf16 bf16x4;
typedef __attribute__((ext_vector_type(4))) float  f32x4;

#define AS1 __attribute__((address_space(1)))
#define AS3 __attribute__((address_space(3)))

// ---------------- combine (+merged prep): single A pass, prefetch-pipelined loads ----------------
// grid: 1024 combine blocks + 640 prep blocks (1D, 1664)

__global__ __launch_bounds__(256, 2)
void k_combine(const float* __restrict__ A,
               const float* __restrict__ w0a, const float* __restrict__ w0b,
               const float* __restrict__ w1,
               bf16_t* __restrict__ Ha, bf16_t* __restrict__ HbT,
               bf16_t* __restrict__ Hb2T, float* __restrict__ part,
               const float* __restrict__ X, const float* __restrict__ l1w,
               const float* __restrict__ l2w, const float* __restrict__ gcnw,
               bf16_t* __restrict__ Xb, bf16_t* __restrict__ l1wb,
               bf16_t* __restrict__ l2wb, bf16_t* __restrict__ gwT) {
  __shared__ bf16_t tl[2][64][65];   // 16.6 KB
  __shared__ float cs[2][4][64];     // 2 KB (per-wave colsum partials)
  int bid = blockIdx.x;
  int t = threadIdx.x;

  if (bid >= 1024) {
    // ---- prep path ----
    int bid2 = bid - 1024;
    if (bid2 < 608) {
      int i = bid2 * 256 + t;
      const float* src; bf16_t* dst; int off;
      if (i < 131072)      { src = X;   dst = Xb;   off = i; }
      else if (i < 147456) { src = l1w; dst = l1wb; off = i - 131072; }
      else                 { src = l2w; dst = l2wb; off = i - 147456; }
      float4 a = ((const float4*)src)[off * 2];
      float4 b = ((const float4*)src)[off * 2 + 1];
      bf16x8 o;
      o[0] = (bf16_t)a.x; o[1] = (bf16_t)a.y; o[2] = (bf16_t)a.z; o[3] = (bf16_t)a.w;
      o[4] = (bf16_t)b.x; o[5] = (bf16_t)b.y; o[6] = (bf16_t)b.z; o[7] = (bf16_t)b.w;
      ((bf16x8*)dst)[off] = o;
    } else {
      int b2 = bid2 - 608;             // 0..31
      int m0 = (b2 & 7) * 64, n0 = (b2 >> 3) * 64;
      int tr = t >> 4, tc = (t & 15) << 2;
      bf16_t (*tile)[65] = (bf16_t (*)[65])&tl[0][0][0];
#pragma unroll
      for (int v = 0; v < 4; ++v) {
        int r = tr + v * 16;
        float4 d = *(const float4*)&gcnw[(long long)(m0 + r) * WOUT + n0 + tc];
        tile[r][tc + 0] = (bf16_t)d.x; tile[r][tc + 1] = (bf16_t)d.y;
        tile[r][tc + 2] = (bf16_t)d.z; tile[r][tc + 3] = (bf16_t)d.w;
      }
      __syncthreads();
#pragma unroll
      for (int v = 0; v < 4; ++v) {
        int r = tr + v * 16;
        bf16x4 o;
        o[0] = tile[tc + 0][r]; o[1] = tile[tc + 1][r];
        o[2] = tile[tc + 2][r]; o[3] = tile[tc + 3][r];
        *(bf16x4*)&gwT[(long long)(n0 + r) * WIN + m0 + tc] = o;
      }
    }
    return;
  }

  // ---- combine path ----
  float f[3][2][5];
  {
    const float* wp[3] = {w0a, w0b, w1};
#pragma unroll
    for (int w = 0; w < 3; ++w)
#pragma unroll
      for (int c = 0; c < 2; ++c) {
        float x[5], m = -1e30f, s = 0.f;
#pragma unroll
        for (int e = 0; e < 5; ++e) { x[e] = wp[w][c * 5 + e]; m = fmaxf(m, x[e]); }
#pragma unroll
        for (int e = 0; e < 5; ++e) { x[e] = expf(x[e] - m); s += x[e]; }
#pragma unroll
        for (int e = 0; e < 5; ++e) f[w][c][e] = x[e] / s;
      }
  }
  int i0 = (bid >> 5) * 64, j0 = (bid & 31) * 64;
  int tr = t >> 4, tc = (t & 15) << 2;
  int lane = t & 63, wid = t >> 6;
  float cs0[4] = {0, 0, 0, 0}, cs1[4] = {0, 0, 0, 0};
  bf16x4 hb2a[4], hb2b[4];

  // prefetch pipeline: q holds v+1's 5 strided float4 loads while v computes
  float4 q[5];
  {
    const float* b0 = A + (long long)(i0 + tr) * NN + j0 + tc;
#pragma unroll
    for (int e = 0; e < 5; ++e) q[e] = *(const float4*)(b0 + (long long)e * N2);
  }
#pragma unroll
  for (int v = 0; v < 4; ++v) {
    int lr = tr + v * 16;
    long long gi = i0 + lr;
    float av[5][4];
#pragma unroll
    for (int e = 0; e < 5; ++e) {
      av[e][0] = q[e].x; av[e][1] = q[e].y; av[e][2] = q[e].z; av[e][3] = q[e].w;
    }
    if (v < 3) {
      const float* bn = A + (gi + 16) * (long long)NN + j0 + tc;
#pragma unroll
      for (int e = 0; e < 5; ++e) q[e] = *(const float4*)(bn + (long long)e * N2);
    }
    bf16x4 ha0, ha1;
#pragma unroll
    for (int x = 0; x < 4; ++x) {
      float s0 = 0.f, s1 = 0.f, s2 = 0.f, s3 = 0.f, s4 = 0.f, s5 = 0.f;
#pragma unroll
      for (int e = 0; e < 5; ++e) {
        float u = av[e][x];
        s0 += f[0][0][e] * u; s1 += f[0][1][e] * u;
        s2 += f[1][0][e] * u; s3 += f[1][1][e] * u;
        s4 += f[2][0][e] * u; s5 += f[2][1][e] * u;
      }
      ha0[x] = (bf16_t)s0; cs0[x] += (float)ha0[x];
      ha1[x] = (bf16_t)s1; cs1[x] += (float)ha1[x];
      tl[0][lr][tc + x] = (bf16_t)s2; tl[1][lr][tc + x] = (bf16_t)s3;
      hb2a[v][x] = (bf16_t)s4; hb2b[v][x] = (bf16_t)s5;
    }
    *(bf16x4*)&Ha[0 * N2 + gi * NN + j0 + tc] = ha0;
    *(bf16x4*)&Ha[1 * N2 + gi * NN + j0 + tc] = ha1;
  }
  // intra-wave reduce over lane>>4 (4 of the 16 row-groups per wave), then LDS
#pragma unroll
  for (int x = 0; x < 4; ++x) {
    float a0 = cs0[x], a1 = cs1[x];
    a0 += __shfl_xor(a0, 16, 64); a0 += __shfl_xor(a0, 32, 64);
    a1 += __shfl_xor(a1, 16, 64); a1 += __shfl_xor(a1, 32, 64);
    if ((lane >> 4) == 0) {
      cs[0][wid][(lane & 15) * 4 + x] = a0;
      cs[1][wid][(lane & 15) * 4 + x] = a1;
    }
  }
  __syncthreads();

#pragma unroll
  for (int v = 0; v < 4; ++v) {
    int lr = tr + v * 16;
#pragma unroll
    for (int ch = 0; ch < 2; ++ch) {
      bf16x4 o;
      o[0] = tl[ch][tc + 0][lr]; o[1] = tl[ch][tc + 1][lr];
      o[2] = tl[ch][tc + 2][lr]; o[3] = tl[ch][tc + 3][lr];
      *(bf16x4*)&HbT[(long long)ch * N2 + (long long)(j0 + lr) * NN + i0 + tc] = o;
    }
  }
  if (t < 128) {
    int ch = t >> 6, col = t & 63;
    float s = cs[ch][0][col] + cs[ch][1][col] + cs[ch][2][col] + cs[ch][3][col];
    part[((long long)ch * 32 + (bid >> 5)) * NN + j0 + col] = s;
  }
  __syncthreads();

#pragma unroll
  for (int v = 0; v < 4; ++v) {
    int lr = tr + v * 16;
#pragma unroll
    for (int x = 0; x < 4; ++x) {
      tl[0][lr][tc + x] = hb2a[v][x];
      tl[1][lr][tc + x] = hb2b[v][x];
    }
  }
  __syncthreads();

#pragma unroll
  for (int v = 0; v < 4; ++v) {
    int lr = tr + v * 16;
#pragma unroll
    for (int ch = 0; ch < 2; ++ch) {
      bf16x4 o;
      o[0] = tl[ch][tc + 0][lr]; o[1] = tl[ch][tc + 1][lr];
      o[2] = tl[ch][tc + 2][lr]; o[3] = tl[ch][tc + 3][lr];
      *(bf16x4*)&Hb2T[(long long)ch * N2 + (long long)(j0 + lr) * NN + i0 + tc] = o;
    }
  }
}

__global__ void k_s_finish(const float* __restrict__ part, float* __restrict__ s) {
  int idx = blockIdx.x * 256 + threadIdx.x;
  int c = idx >> 11, k = idx & 2047;
  float acc = 0.f;
#pragma unroll
  for (int ib = 0; ib < 32; ++ib) acc += part[((long long)c * 32 + ib) * NN + k];
  s[idx] = acc;
}

// deg[c][j] = sum_k (svec[k] - A[j,k])*BT[j,k];  Mdiag[c][j] = sum_k A[j,k]*BT[j,k]
template<bool EMIT_DIS>
__global__ void k_deg(const float* __restrict__ svec, const bf16_t* __restrict__ Arows,
                      const bf16_t* __restrict__ BT,
                      float* __restrict__ out1, float* __restrict__ out2,
                      float* __restrict__ out3) {
  int c = blockIdx.y;
  int j = blockIdx.x * 4 + (threadIdx.x >> 6);
  int lane = threadIdx.x & 63;
  const bf16_t* a = Arows + (long long)c * N2 + (long long)j * NN;
  const bf16_t* b = BT + (long long)c * N2 + (long long)j * NN;
  const float* s = svec + c * NN;
  float acc_s = 0.f, acc_a = 0.f;
#pragma unroll
  for (int it = 0; it < 4; ++it) {
    int k0 = (lane + it * 64) * 8;
    bf16x8 av = *(const bf16x8*)(a + k0);
    bf16x8 bv = *(const bf16x8*)(b + k0);
    float4 s0 = *(const float4*)(s + k0);
    float4 s1 = *(const float4*)(s + k0 + 4);
    float sv[8] = {s0.x, s0.y, s0.z, s0.w, s1.x, s1.y, s1.z, s1.w};
#pragma unroll
    for (int x = 0; x < 8; ++x) {
      float bx = (float)bv[x];
      acc_s += sv[x] * bx;
      acc_a += (float)av[x] * bx;
    }
  }
#pragma unroll
  for (int o = 32; o > 0; o >>= 1) {
    acc_s += __shfl_xor(acc_s, o, 64);
    acc_a += __shfl_xor(acc_a, o, 64);
  }
  if (lane == 0) {
    float deg = acc_s - acc_a;
    bool nz = (deg != 0.f);
    if (!EMIT_DIS) {
      out1[c * NN + j] = nz ? 1.f / deg : 0.f;
      out2[c * NN + j] = nz ? 1.f : 0.f;
    } else {
      float dis = nz ? 0.70710678118654752f : 1.f;
      out1[c * NN + j] = nz ? dis / deg : 0.f;     // cscal
      out2[c * NN + j] = dis;                      // disv
      out3[c * NN + j] = acc_a;                    // Mdiag
    }
  }
}

// ---------------- GEMM1: 128x128 tile, BK=64 slots (2x BK32 sub-tiles), ring-2 (R8 config) ----------------

__global__ __launch_bounds__(256)
void k_gemmL(const bf16_t* __restrict__ A, const bf16_t* __restrict__ B,
             bf16_t* __restrict__ Hn, bf16_t* __restrict__ HnT,
             const float* __restrict__ dinv) {
  __shared__ __align__(16) char smem[65536];
  bf16_t* As = (bf16_t*)smem;
  bf16_t* Bs = (bf16_t*)(smem + 32768);
  bf16_t* tile = (bf16_t*)smem;

  int cz = blockIdx.z;
  const bf16_t* Ab = A + cz * N2 + (long long)blockIdx.x * 128 * NN;
  const bf16_t* Bb = B + cz * N2 + (long long)blockIdx.y * 128 * NN;

  int t = threadIdx.x, wid = t >> 6, lane = t & 63;
  int wr = wid >> 1, wc = wid & 1;
  f32x4 acc[4][4] = {};
  int frow = lane & 15;
  int fk_sw = (((lane >> 4) ^ ((frow >> 1) & 3)) << 3);
  int srow = t >> 2;
  int scol_sw = (((t & 3) ^ ((t >> 3) & 3)) << 3);

  auto STAGE = [&](int TT, int BUF) {
#pragma unroll
    for (int s = 0; s < 2; ++s) {
      long long kko = (long long)TT * 64 + s * 32 + scol_sw;
      const bf16_t* ga0 = Ab + (long long)srow * NN + kko;
      const bf16_t* gb0 = Bb + (long long)srow * NN + kko;
      char* la = smem + BUF * 16384 + s * 8192 + wid * 1024;
      char* lb = smem + 32768 + BUF * 16384 + s * 8192 + wid * 1024;
      __builtin_amdgcn_global_load_lds((AS1 void*)ga0, (AS3 void*)la, 16, 0, 0);
      __builtin_amdgcn_global_load_lds((AS1 void*)(ga0 + 64LL * NN), (AS3 void*)(la + 4096), 16, 0, 0);
      __builtin_amdgcn_global_load_lds((AS1 void*)gb0, (AS3 void*)lb, 16, 0, 0);
      __builtin_amdgcn_global_load_lds((AS1 void*)(gb0 + 64LL * NN), (AS3 void*)(lb + 4096), 16, 0, 0);
    }
  };
  auto COMPUTE = [&](int BUF) {
#pragma unroll
    for (int ks = 0; ks < 2; ++ks) {
      bf16x8 af[4], bfr[4];
#pragma unroll
      for (int m = 0; m < 4; ++m)
        af[m] = *(const bf16x8*)&As[BUF * 8192 + ks * 4096 + (wr * 64 + m * 16 + frow) * 32 + fk_sw];
#pragma unroll
      for (int n = 0; n < 4; ++n)
        bfr[n] = *(const bf16x8*)&Bs[BUF * 8192 + ks * 4096 + (wc * 64 + n * 16 + frow) * 32 + fk_sw];
      __builtin_amdgcn_s_setprio(1);
#pragma unroll
      for (int m = 0; m < 4; ++m)
#pragma unroll
        for (int n = 0; n < 4; ++n)
          acc[m][n] = __builtin_amdgcn_mfma_f32_16x16x32_bf16(af[m], bfr[n], acc[m][n], 0, 0, 0);
      __builtin_amdgcn_s_setprio(0);
    }
  };

  const int nt = 32;  // K/64
  STAGE(0, 0); STAGE(1, 1);
  for (int tt = 0; tt < nt; ++tt) {
    if (tt < nt - 1) asm volatile("s_waitcnt vmcnt(8)" ::: "memory");
    else             asm volatile("s_waitcnt vmcnt(0)" ::: "memory");
    __builtin_amdgcn_s_barrier();
    __builtin_amdgcn_sched_barrier(0);
    COMPUTE(tt & 1);
    __builtin_amdgcn_s_barrier();
    if (tt + 2 < nt) STAGE(tt + 2, tt & 1);
  }
  __builtin_amdgcn_sched_barrier(0);

  int rl0 = wr * 64 + ((lane >> 4) << 2);
  int cl0 = wc * 64 + (lane & 15);
  int r0 = blockIdx.x * 128 + rl0;
  int c0 = blockIdx.y * 128 + cl0;

  bf16_t* Cb = Hn + cz * N2;
  bf16_t* Ct = HnT + cz * N2;
  float dj[4];
#pragma unroll
  for (int n = 0; n < 4; ++n) dj[n] = dinv[cz * NN + c0 + n * 16];
#pragma unroll
  for (int m = 0; m < 4; ++m)
#pragma unroll
    for (int n = 0; n < 4; ++n)
#pragma unroll
      for (int j = 0; j < 4; ++j) {
        int r = r0 + m * 16 + j, col = c0 + n * 16;
        float v = (r == col) ? 0.f : acc[m][n][j] * dj[n];
        Cb[(long long)r * NN + col] = (bf16_t)v;
        tile[(rl0 + m * 16 + j) * 130 + cl0 + n * 16] = (bf16_t)v;
      }
  __syncthreads();
  int nl = t >> 5, rl = (t & 31) * 4;
#pragma unroll
  for (int vv = 0; vv < 16; ++vv) {
    int n_l = nl + vv * 8;
    bf16x4 o;
    o[0] = tile[(rl + 0) * 130 + n_l]; o[1] = tile[(rl + 1) * 130 + n_l];
    o[2] = tile[(rl + 2) * 130 + n_l]; o[3] = tile[(rl + 3) * 130 + n_l];
    *(bf16x4*)&Ct[(long long)(blockIdx.y * 128 + n_l) * NN + blockIdx.x * 128 + rl] = o;
  }
}

// ---------------- bf16 GEMM, 128x64 tile, ring-3, counted vmcnt, swizzle, fused epilogues ----------------

enum { EP_BRELU = 3, EP_BF32 = 4, EP_BF16O = 7, EP_XWDT = 8, EP_GCN = 9 };

template<int EP>
__global__ __launch_bounds__(256)
void k_gemm(const bf16_t* __restrict__ A, const bf16_t* __restrict__ B,
            void* __restrict__ Cv,
            const float* __restrict__ aux1, const float* __restrict__ aux2,
            bf16_t* __restrict__ aux3, const float* __restrict__ aux4,
            int N, int K, int lda, int ldb,
            long long zA, long long zB, long long zC) {
  __shared__ __align__(16) char smem[36864];
  bf16_t* As = (bf16_t*)smem;
  bf16_t* Bs = (bf16_t*)(smem + 24576);
  bf16_t* tile = (bf16_t*)smem;

  int cz = blockIdx.z;
  const bf16_t* Ab = A + cz * zA + (long long)blockIdx.x * 128 * lda;
  const bf16_t* Bb = B + cz * zB + (long long)blockIdx.y * 64 * ldb;

  int t = threadIdx.x, wid = t >> 6, lane = t & 63;
  int wr = wid >> 1, wc = wid & 1;
  f32x4 acc[4][2] = {};
  int frow = lane & 15;
  int fk_sw = (((lane >> 4) ^ ((frow >> 1) & 3)) << 3);
  int srow = t >> 2;
  int scol_sw = (((t & 3) ^ ((t >> 3) & 3)) << 3);
  int nt = K >> 5;

  auto STAGE = [&](int TT, int BUF) {
    long long kko = (long long)TT * 32 + scol_sw;
    const bf16_t* ga0 = Ab + (long long)srow * lda + kko;
    const bf16_t* ga1 = Ab + (long long)(64 + srow) * lda + kko;
    const bf16_t* gb0 = Bb + (long long)srow * ldb + kko;
    char* la = smem + BUF * 8192 + wid * 1024;
    char* lb = smem + 24576 + BUF * 4096 + wid * 1024;
    __builtin_amdgcn_global_load_lds((AS1 void*)ga0, (AS3 void*)la, 16, 0, 0);
    __builtin_amdgcn_global_load_lds((AS1 void*)ga1, (AS3 void*)(la + 4096), 16, 0, 0);
    __builtin_amdgcn_global_load_lds((AS1 void*)gb0, (AS3 void*)lb, 16, 0, 0);
  };
  auto COMPUTE = [&](int BUF) {
    bf16x8 af[4], bfr[2];
#pragma unroll
    for (int m = 0; m < 4; ++m)
      af[m] = *(const bf16x8*)&As[BUF * 4096 + (wr * 64 + m * 16 + frow) * 32 + fk_sw];
#pragma unroll
    for (int n = 0; n < 2; ++n)
      bfr[n] = *(const bf16x8*)&Bs[BUF * 2048 + (wc * 32 + n * 16 + frow) * 32 + fk_sw];
#pragma unroll
    for (int m = 0; m < 4; ++m)
#pragma unroll
      for (int n = 0; n < 2; ++n)
        acc[m][n] = __builtin_amdgcn_mfma_f32_16x16x32_bf16(af[m], bfr[n], acc[m][n], 0, 0, 0);
  };

  STAGE(0, 0); STAGE(1, 1); STAGE(2, 2);
  int slot = 0;
  for (int tt = 0; tt < nt; ++tt) {
    int rem = nt - 1 - tt;
    if (rem >= 2)      asm volatile("s_waitcnt vmcnt(6)" ::: "memory");
    else if (rem == 1) asm volatile("s_waitcnt vmcnt(3)" ::: "memory");
    else               asm volatile("s_waitcnt vmcnt(0)" ::: "memory");
    __builtin_amdgcn_s_barrier();
    __builtin_amdgcn_sched_barrier(0);
    COMPUTE(slot);
    __builtin_amdgcn_s_barrier();
    if (tt + 3 < nt) STAGE(tt + 3, slot);
    slot = (slot == 2) ? 0 : slot + 1;
  }
  __builtin_amdgcn_sched_barrier(0);

  int rl0 = wr * 64 + ((lane >> 4) << 2);
  int cl0 = wc * 32 + (lane & 15);
  int r0 = blockIdx.x * 128 + rl0;
  int c0 = blockIdx.y * 64 + cl0;

  if constexpr (EP == EP_BF16O) {
    bf16_t* Cb = (bf16_t*)Cv + cz * zC;
#pragma unroll
    for (int m = 0; m < 4; ++m)
#pragma unroll
      for (int n = 0; n < 2; ++n)
#pragma unroll
        for (int j = 0; j < 4; ++j)
          Cb[(long long)(r0 + m * 16 + j) * N + c0 + n * 16] = (bf16_t)acc[m][n][j];
  } else if constexpr (EP == EP_XWDT) {
    float* Cb = (float*)Cv;
#pragma unroll
    for (int m = 0; m < 4; ++m)
#pragma unroll
      for (int n = 0; n < 2; ++n)
#pragma unroll
        for (int j = 0; j < 4; ++j) {
          float v = acc[m][n][j];
          Cb[(long long)(r0 + m * 16 + j) * N + c0 + n * 16] = v;
          tile[(rl0 + m * 16 + j) * 65 + cl0 + n * 16] = (bf16_t)v;
        }
    __syncthreads();
    int nl = t >> 5, rl = (t & 31) * 4;
#pragma unroll
    for (int vv = 0; vv < 8; ++vv) {
      int n_l = nl + vv * 8;
      bf16x4 v4;
      v4[0] = tile[(rl + 0) * 65 + n_l]; v4[1] = tile[(rl + 1) * 65 + n_l];
      v4[2] = tile[(rl + 2) * 65 + n_l]; v4[3] = tile[(rl + 3) * 65 + n_l];
      int i0 = blockIdx.x * 128 + rl;
      long long row = (long long)(blockIdx.y * 64 + n_l) * NN + i0;
#pragma unroll
      for (int c = 0; c < 2; ++c) {
        float4 dv = *(const float4*)&aux2[c * NN + i0];  // disv
        bf16x4 o;
        o[0] = (bf16_t)((float)v4[0] * dv.x); o[1] = (bf16_t)((float)v4[1] * dv.y);
        o[2] = (bf16_t)((float)v4[2] * dv.z); o[3] = (bf16_t)((float)v4[3] * dv.w);
        *(bf16x4*)&aux3[(long long)c * WOUT * NN + row] = o;
      }
    }
  } else if constexpr (EP == EP_GCN) {
    bf16_t* Cb = (bf16_t*)Cv;
    const float* XWp = aux1;
    const float* csp = aux2 + cz * NN;
    const float* dnp = aux2 + CC * NN + cz * NN;
    const float* mdp = aux2 + 2 * CC * NN + cz * NN;
    float bj[2];
#pragma unroll
    for (int n = 0; n < 2; ++n) bj[n] = aux4[c0 + n * 16];
#pragma unroll
    for (int m = 0; m < 4; ++m)
#pragma unroll
      for (int j = 0; j < 4; ++j) {
        int r = r0 + m * 16 + j;
        float csv = csp[r], dnv = dnp[r], mdv = mdp[r];
        float mdd = mdv * dnv, d2 = dnv * dnv;
#pragma unroll
        for (int n = 0; n < 2; ++n) {
          float xw = XWp[(long long)r * WOUT + c0 + n * 16];
          float v = fmaxf(csv * (acc[m][n][j] - mdd * xw) + d2 * xw + bj[n], 0.f);
          Cb[(long long)r * (CC * WOUT) + cz * WOUT + c0 + n * 16] = (bf16_t)v;
        }
      }
  } else if constexpr (EP == EP_BRELU) {
    bf16_t* Cb = (bf16_t*)Cv;
    float bj[2];
#pragma unroll
    for (int n = 0; n < 2; ++n) bj[n] = aux1[c0 + n * 16];
#pragma unroll
    for (int m = 0; m < 4; ++m)
#pragma unroll
      for (int n = 0; n < 2; ++n)
#pragma unroll
        for (int j = 0; j < 4; ++j)
          Cb[(long long)(r0 + m * 16 + j) * N + c0 + n * 16] =
              (bf16_t)fmaxf(acc[m][n][j] + bj[n], 0.f);
  } else { // EP_BF32
    float* Cb = (float*)Cv;
    float bj[2];
#pragma unroll
    for (int n = 0; n < 2; ++n) bj[n] = aux1[c0 + n * 16];
#pragma unroll
    for (int m = 0; m < 4; ++m)
#pragma unroll
      for (int n = 0; n < 2; ++n)
#pragma unroll
        for (int j = 0; j < 4; ++j)
          Cb[(long long)(r0 + m * 16 + j) * N + c0 + n * 16] = acc[m][n][j] + bj[n];
  }
}

// ---------------- launch ----------------

extern "C" void kernel_launch(void* const* d_in, const int* in_sizes, int n_in,
                              void* d_out, int out_size, void* d_ws, size_t ws_size,
                              hipStream_t stream) {
  const float* A    = (const float*)d_in[0];
  const float* X    = (const float*)d_in[1];
  const float* w0a  = (const float*)d_in[2];
  const float* w0b  = (const float*)d_in[3];
  const float* w1   = (const float*)d_in[4];
  const float* gcnw = (const float*)d_in[5];
  const float* gcnb = (const float*)d_in[6];
  const float* l1w  = (const float*)d_in[7];
  const float* l1b  = (const float*)d_in[8];
  const float* l2w  = (const float*)d_in[9];
  const float* l2b  = (const float*)d_in[10];
  float* out = (float*)d_out;

  char* p = (char*)d_ws;
  auto carve = [&](size_t bytes) -> char* {
    char* r = p; p += (bytes + 255) & ~(size_t)255; return r;
  };
  float*  svec  = (float*)carve((size_t)CC * NN * 4);
  float*  dinv1 = (float*)carve((size_t)CC * NN * 4);
  float*  m1    = (float*)carve((size_t)CC * NN * 4);
  float*  scal  = (float*)carve((size_t)3 * CC * NN * 4);  // cscal | disv | Mdiag
  float*  part  = (float*)carve((size_t)CC * 32 * NN * 4);
  bf16_t* S1    = (bf16_t*)carve((size_t)CC * N2 * 2);  // Ha -> {XWdT, Yt}
  bf16_t* HbT   = (bf16_t*)carve((size_t)CC * N2 * 2);
  bf16_t* Hb2T  = (bf16_t*)carve((size_t)CC * N2 * 2);
  bf16_t* Hn    = (bf16_t*)carve((size_t)CC * N2 * 2);
  bf16_t* HnT   = (bf16_t*)carve((size_t)CC * N2 * 2);
  bf16_t* Xb    = (bf16_t*)carve((size_t)NN * WIN * 2);
  bf16_t* gwT   = (bf16_t*)carve((size_t)WOUT * WIN * 2);
  bf16_t* l1wb  = (bf16_t*)carve((size_t)WOUT * CC * WOUT * 2);
  bf16_t* l2wb  = (bf16_t*)carve((size_t)WOUT * WOUT * 2);
  float*  XW    = (float*)carve((size_t)NN * WOUT * 4);
  bf16_t* Xcat  = (bf16_t*)carve((size_t)NN * CC * WOUT * 2);
  bf16_t* hb    = (bf16_t*)carve((size_t)NN * WOUT * 2);

  bf16_t* Ha = S1;
  bf16_t* XWdT = (bf16_t*)((char*)S1);                 // 2 MB
  bf16_t* Yt   = (bf16_t*)((char*)S1 + (2LL << 20));   // 2 MB
  float*  disv = scal + CC * NN;

  // combine (+merged prep)
  k_combine<<<1664, 256, 0, stream>>>(A, w0a, w0b, w1, Ha, HbT, Hb2T, part,
                                      X, l1w, l2w, gcnw, Xb, l1wb, l2wb, gwT);
  k_s_finish<<<16, 256, 0, stream>>>(part, svec);

  // layer 0: analytic degrees; GEMM1 (R8 config) fused normalize -> Hn + HnT
  k_deg<false><<<dim3(512, 2), 256, 0, stream>>>(svec, Ha, HbT, dinv1, m1, nullptr);
  k_gemmL<<<dim3(16, 16, 2), 256, 0, stream>>>(Ha, HbT, Hn, HnT, dinv1);

  // layer 1 scalars (packed: cscal | disv | Mdiag)
  k_deg<true><<<dim3(512, 2), 256, 0, stream>>>(m1, Hn, Hb2T,
                                                scal, scal + CC * NN, scal + 2 * CC * NN);

  // GCN via associativity: XW (+fused disv-scaled transpose -> XWdT both channels);
  // Yt = XWdT @ HnT^T; Xcat = gcn-epilogue(Hb2T @ Yt^T)
  k_gemm<EP_XWDT><<<dim3(16, 4, 1), 256, 0, stream>>>(
      Xb, gwT, XW, nullptr, disv, XWdT, nullptr, WOUT, WIN, WIN, WIN, 0, 0, 0);
  k_gemm<EP_BF16O><<<dim3(2, 32, 2), 256, 0, stream>>>(
      XWdT, HnT, Yt, nullptr, nullptr, nullptr, nullptr, NN, NN, NN, NN,
      (long long)WOUT * NN, N2, (long long)WOUT * NN);
  k_gemm<EP_GCN><<<dim3(16, 4, 2), 256, 0, stream>>>(
      Hb2T, Yt, Xcat, XW, scal, nullptr, gcnb, WOUT, NN, NN, NN,
      N2, (long long)WOUT * NN, 0);

  // MLP with fused bias(+relu)
  k_gemm<EP_BRELU><<<dim3(16, 4, 1), 256, 0, stream>>>(
      Xcat, l1wb, hb, l1b, nullptr, nullptr, nullptr, WOUT, CC * WOUT, CC * WOUT, CC * WOUT, 0, 0, 0);
  k_gemm<EP_BF32><<<dim3(16, 4, 1), 256, 0, stream>>>(
      hb, l2wb, out, l2b, nullptr, nullptr, nullptr, WOUT, WOUT, WOUT, WOUT, 0, 0, 0);
}

// Round 14
// 141.234 us; speedup vs baseline: 1.1674x; 1.0081x over previous
//
#include <hip/hip_runtime.h>
#include <cstdint>
#include <cstddef>

#define NN   2048
#define N2   (2048LL*2048LL)
#define CC   2
#define EE   5
#define WIN  512
#define WOUT 256

typedef __bf16 bf16_t;
typedef __attribute__((ext_vector_type(8))) __bf16 bf16x8;
typedef __attribute__((ext_vector_type(4))) __bf16 bf16x4;
typedef __attribute__((ext_vector_type(4))) float  f32x4;

#define AS1 __attribute__((address_space(1)))
#define AS3 __attribute__((address_space(3)))

// ---------------- combine (+merged prep): single A pass, prefetch-pipelined loads ----------------
// grid: 1024 combine blocks + 640 prep blocks (1D, 1664)

__global__ __launch_bounds__(256, 2)
void k_combine(const float* __restrict__ A,
               const float* __restrict__ w0a, const float* __restrict__ w0b,
               const float* __restrict__ w1,
               bf16_t* __restrict__ Ha, bf16_t* __restrict__ HbT,
               bf16_t* __restrict__ Hb2T, float* __restrict__ part,
               const float* __restrict__ X, const float* __restrict__ l1w,
               const float* __restrict__ l2w, const float* __restrict__ gcnw,
               bf16_t* __restrict__ Xb, bf16_t* __restrict__ l1wb,
               bf16_t* __restrict__ l2wb, bf16_t* __restrict__ gwT) {
  __shared__ bf16_t tl[2][64][65];   // 16.6 KB
  __shared__ float cs[2][4][64];     // 2 KB (per-wave colsum partials)
  int bid = blockIdx.x;
  int t = threadIdx.x;

  if (bid >= 1024) {
    // ---- prep path ----
    int bid2 = bid - 1024;
    if (bid2 < 608) {
      int i = bid2 * 256 + t;
      const float* src; bf16_t* dst; int off;
      if (i < 131072)      { src = X;   dst = Xb;   off = i; }
      else if (i < 147456) { src = l1w; dst = l1wb; off = i - 131072; }
      else                 { src = l2w; dst = l2wb; off = i - 147456; }
      float4 a = ((const float4*)src)[off * 2];
      float4 b = ((const float4*)src)[off * 2 + 1];
      bf16x8 o;
      o[0] = (bf16_t)a.x; o[1] = (bf16_t)a.y; o[2] = (bf16_t)a.z; o[3] = (bf16_t)a.w;
      o[4] = (bf16_t)b.x; o[5] = (bf16_t)b.y; o[6] = (bf16_t)b.z; o[7] = (bf16_t)b.w;
      ((bf16x8*)dst)[off] = o;
    } else {
      int b2 = bid2 - 608;             // 0..31
      int m0 = (b2 & 7) * 64, n0 = (b2 >> 3) * 64;
      int tr = t >> 4, tc = (t & 15) << 2;
      bf16_t (*tile)[65] = (bf16_t (*)[65])&tl[0][0][0];
#pragma unroll
      for (int v = 0; v < 4; ++v) {
        int r = tr + v * 16;
        float4 d = *(const float4*)&gcnw[(long long)(m0 + r) * WOUT + n0 + tc];
        tile[r][tc + 0] = (bf16_t)d.x; tile[r][tc + 1] = (bf16_t)d.y;
        tile[r][tc + 2] = (bf16_t)d.z; tile[r][tc + 3] = (bf16_t)d.w;
      }
      __syncthreads();
#pragma unroll
      for (int v = 0; v < 4; ++v) {
        int r = tr + v * 16;
        bf16x4 o;
        o[0] = tile[tc + 0][r]; o[1] = tile[tc + 1][r];
        o[2] = tile[tc + 2][r]; o[3] = tile[tc + 3][r];
        *(bf16x4*)&gwT[(long long)(n0 + r) * WIN + m0 + tc] = o;
      }
    }
    return;
  }

  // ---- combine path ----
  float f[3][2][5];
  {
    const float* wp[3] = {w0a, w0b, w1};
#pragma unroll
    for (int w = 0; w < 3; ++w)
#pragma unroll
      for (int c = 0; c < 2; ++c) {
        float x[5], m = -1e30f, s = 0.f;
#pragma unroll
        for (int e = 0; e < 5; ++e) { x[e] = wp[w][c * 5 + e]; m = fmaxf(m, x[e]); }
#pragma unroll
        for (int e = 0; e < 5; ++e) { x[e] = expf(x[e] - m); s += x[e]; }
#pragma unroll
        for (int e = 0; e < 5; ++e) f[w][c][e] = x[e] / s;
      }
  }
  int i0 = (bid >> 5) * 64, j0 = (bid & 31) * 64;
  int tr = t >> 4, tc = (t & 15) << 2;
  int lane = t & 63, wid = t >> 6;
  float cs0[4] = {0, 0, 0, 0}, cs1[4] = {0, 0, 0, 0};
  bf16x4 hb2a[4], hb2b[4];

  float4 q[5];
  {
    const float* b0 = A + (long long)(i0 + tr) * NN + j0 + tc;
#pragma unroll
    for (int e = 0; e < 5; ++e) q[e] = *(const float4*)(b0 + (long long)e * N2);
  }
#pragma unroll
  for (int v = 0; v < 4; ++v) {
    int lr = tr + v * 16;
    long long gi = i0 + lr;
    float av[5][4];
#pragma unroll
    for (int e = 0; e < 5; ++e) {
      av[e][0] = q[e].x; av[e][1] = q[e].y; av[e][2] = q[e].z; av[e][3] = q[e].w;
    }
    if (v < 3) {
      const float* bn = A + (gi + 16) * (long long)NN + j0 + tc;
#pragma unroll
      for (int e = 0; e < 5; ++e) q[e] = *(const float4*)(bn + (long long)e * N2);
    }
    bf16x4 ha0, ha1;
#pragma unroll
    for (int x = 0; x < 4; ++x) {
      float s0 = 0.f, s1 = 0.f, s2 = 0.f, s3 = 0.f, s4 = 0.f, s5 = 0.f;
#pragma unroll
      for (int e = 0; e < 5; ++e) {
        float u = av[e][x];
        s0 += f[0][0][e] * u; s1 += f[0][1][e] * u;
        s2 += f[1][0][e] * u; s3 += f[1][1][e] * u;
        s4 += f[2][0][e] * u; s5 += f[2][1][e] * u;
      }
      ha0[x] = (bf16_t)s0; cs0[x] += (float)ha0[x];
      ha1[x] = (bf16_t)s1; cs1[x] += (float)ha1[x];
      tl[0][lr][tc + x] = (bf16_t)s2; tl[1][lr][tc + x] = (bf16_t)s3;
      hb2a[v][x] = (bf16_t)s4; hb2b[v][x] = (bf16_t)s5;
    }
    *(bf16x4*)&Ha[0 * N2 + gi * NN + j0 + tc] = ha0;
    *(bf16x4*)&Ha[1 * N2 + gi * NN + j0 + tc] = ha1;
  }
#pragma unroll
  for (int x = 0; x < 4; ++x) {
    float a0 = cs0[x], a1 = cs1[x];
    a0 += __shfl_xor(a0, 16, 64); a0 += __shfl_xor(a0, 32, 64);
    a1 += __shfl_xor(a1, 16, 64); a1 += __shfl_xor(a1, 32, 64);
    if ((lane >> 4) == 0) {
      cs[0][wid][(lane & 15) * 4 + x] = a0;
      cs[1][wid][(lane & 15) * 4 + x] = a1;
    }
  }
  __syncthreads();

#pragma unroll
  for (int v = 0; v < 4; ++v) {
    int lr = tr + v * 16;
#pragma unroll
    for (int ch = 0; ch < 2; ++ch) {
      bf16x4 o;
      o[0] = tl[ch][tc + 0][lr]; o[1] = tl[ch][tc + 1][lr];
      o[2] = tl[ch][tc + 2][lr]; o[3] = tl[ch][tc + 3][lr];
      *(bf16x4*)&HbT[(long long)ch * N2 + (long long)(j0 + lr) * NN + i0 + tc] = o;
    }
  }
  if (t < 128) {
    int ch = t >> 6, col = t & 63;
    float s = cs[ch][0][col] + cs[ch][1][col] + cs[ch][2][col] + cs[ch][3][col];
    part[((long long)ch * 32 + (bid >> 5)) * NN + j0 + col] = s;
  }
  __syncthreads();

#pragma unroll
  for (int v = 0; v < 4; ++v) {
    int lr = tr + v * 16;
#pragma unroll
    for (int x = 0; x < 4; ++x) {
      tl[0][lr][tc + x] = hb2a[v][x];
      tl[1][lr][tc + x] = hb2b[v][x];
    }
  }
  __syncthreads();

#pragma unroll
  for (int v = 0; v < 4; ++v) {
    int lr = tr + v * 16;
#pragma unroll
    for (int ch = 0; ch < 2; ++ch) {
      bf16x4 o;
      o[0] = tl[ch][tc + 0][lr]; o[1] = tl[ch][tc + 1][lr];
      o[2] = tl[ch][tc + 2][lr]; o[3] = tl[ch][tc + 3][lr];
      *(bf16x4*)&Hb2T[(long long)ch * N2 + (long long)(j0 + lr) * NN + i0 + tc] = o;
    }
  }
}

__global__ void k_s_finish(const float* __restrict__ part, float* __restrict__ s) {
  int idx = blockIdx.x * 256 + threadIdx.x;
  int c = idx >> 11, k = idx & 2047;
  float acc = 0.f;
#pragma unroll
  for (int ib = 0; ib < 32; ++ib) acc += part[((long long)c * 32 + ib) * NN + k];
  s[idx] = acc;
}

// deg1[c][j] = sum_k (svec[k] - Ha[j,k])*HbT[j,k]  -> dinv1, m1
__global__ void k_deg1(const float* __restrict__ svec, const bf16_t* __restrict__ Arows,
                       const bf16_t* __restrict__ BT,
                       float* __restrict__ out1, float* __restrict__ out2) {
  int c = blockIdx.y;
  int j = blockIdx.x * 4 + (threadIdx.x >> 6);
  int lane = threadIdx.x & 63;
  const bf16_t* a = Arows + (long long)c * N2 + (long long)j * NN;
  const bf16_t* b = BT + (long long)c * N2 + (long long)j * NN;
  const float* s = svec + c * NN;
  float acc_s = 0.f, acc_a = 0.f;
#pragma unroll
  for (int it = 0; it < 4; ++it) {
    int k0 = (lane + it * 64) * 8;
    bf16x8 av = *(const bf16x8*)(a + k0);
    bf16x8 bv = *(const bf16x8*)(b + k0);
    float4 s0 = *(const float4*)(s + k0);
    float4 s1 = *(const float4*)(s + k0 + 4);
    float sv[8] = {s0.x, s0.y, s0.z, s0.w, s1.x, s1.y, s1.z, s1.w};
#pragma unroll
    for (int x = 0; x < 8; ++x) {
      float bx = (float)bv[x];
      acc_s += sv[x] * bx;
      acc_a += (float)av[x] * bx;
    }
  }
#pragma unroll
  for (int o = 32; o > 0; o >>= 1) {
    acc_s += __shfl_xor(acc_s, o, 64);
    acc_a += __shfl_xor(acc_a, o, 64);
  }
  if (lane == 0) {
    float deg = acc_s - acc_a;
    bool nz = (deg != 0.f);
    out1[c * NN + j] = nz ? 1.f / deg : 0.f;
    out2[c * NN + j] = nz ? 1.f : 0.f;
  }
}

// reduce per-by deg2/Mdiag partials -> scal (cscal | disv | Mdiag)
__global__ void k_deg2_finish(const float* __restrict__ pd, const float* __restrict__ pm,
                              float* __restrict__ scal) {
  int idx = blockIdx.x * 256 + threadIdx.x;  // 4096 = c*2048 + r
  int c = idx >> 11, r = idx & 2047;
  float deg = 0.f, md = 0.f;
#pragma unroll
  for (int by = 0; by < 16; ++by) {
    deg += pd[((long long)by * CC + c) * NN + r];
    md  += pm[((long long)by * CC + c) * NN + r];
  }
  bool nz = (deg != 0.f);
  float dis = nz ? 0.70710678118654752f : 1.f;
  scal[c * NN + r] = nz ? dis / deg : 0.f;
  scal[CC * NN + c * NN + r] = dis;
  scal[2 * CC * NN + c * NN + r] = md;
}

// ---------------- GEMM1: 128x128 tile, BK=64 ring-2 (R8 config); epilogue emits HnT + deg2/Mdiag partials ----------------

__global__ __launch_bounds__(256)
void k_gemmL(const bf16_t* __restrict__ A, const bf16_t* __restrict__ B,
             bf16_t* __restrict__ HnT, const float* __restrict__ dinv,
             const float* __restrict__ m1, const bf16_t* __restrict__ Hb2T,
             float* __restrict__ pd, float* __restrict__ pm) {
  __shared__ __align__(16) char smem[65536];
  bf16_t* As = (bf16_t*)smem;
  bf16_t* Bs = (bf16_t*)(smem + 32768);
  bf16_t* tile = (bf16_t*)smem;                 // epilogue: 128x130 bf16 = 33.3 KB
  float* sbd = (float*)(smem + 34816);          // 4 wid x 64 rows
  float* sbm = (float*)(smem + 34816 + 1024);

  int cz = blockIdx.z;
  const bf16_t* Ab = A + cz * N2 + (long long)blockIdx.x * 128 * NN;
  const bf16_t* Bb = B + cz * N2 + (long long)blockIdx.y * 128 * NN;

  int t = threadIdx.x, wid = t >> 6, lane = t & 63;
  int wr = wid >> 1, wc = wid & 1;
  f32x4 acc[4][4] = {};
  int frow = lane & 15;
  int fk_sw = (((lane >> 4) ^ ((frow >> 1) & 3)) << 3);
  int srow = t >> 2;
  int scol_sw = (((t & 3) ^ ((t >> 3) & 3)) << 3);

  auto STAGE = [&](int TT, int BUF) {
#pragma unroll
    for (int s = 0; s < 2; ++s) {
      long long kko = (long long)TT * 64 + s * 32 + scol_sw;
      const bf16_t* ga0 = Ab + (long long)srow * NN + kko;
      const bf16_t* gb0 = Bb + (long long)srow * NN + kko;
      char* la = smem + BUF * 16384 + s * 8192 + wid * 1024;
      char* lb = smem + 32768 + BUF * 16384 + s * 8192 + wid * 1024;
      __builtin_amdgcn_global_load_lds((AS1 void*)ga0, (AS3 void*)la, 16, 0, 0);
      __builtin_amdgcn_global_load_lds((AS1 void*)(ga0 + 64LL * NN), (AS3 void*)(la + 4096), 16, 0, 0);
      __builtin_amdgcn_global_load_lds((AS1 void*)gb0, (AS3 void*)lb, 16, 0, 0);
      __builtin_amdgcn_global_load_lds((AS1 void*)(gb0 + 64LL * NN), (AS3 void*)(lb + 4096), 16, 0, 0);
    }
  };
  auto COMPUTE = [&](int BUF) {
#pragma unroll
    for (int ks = 0; ks < 2; ++ks) {
      bf16x8 af[4], bfr[4];
#pragma unroll
      for (int m = 0; m < 4; ++m)
        af[m] = *(const bf16x8*)&As[BUF * 8192 + ks * 4096 + (wr * 64 + m * 16 + frow) * 32 + fk_sw];
#pragma unroll
      for (int n = 0; n < 4; ++n)
        bfr[n] = *(const bf16x8*)&Bs[BUF * 8192 + ks * 4096 + (wc * 64 + n * 16 + frow) * 32 + fk_sw];
      __builtin_amdgcn_s_setprio(1);
#pragma unroll
      for (int m = 0; m < 4; ++m)
#pragma unroll
        for (int n = 0; n < 4; ++n)
          acc[m][n] = __builtin_amdgcn_mfma_f32_16x16x32_bf16(af[m], bfr[n], acc[m][n], 0, 0, 0);
      __builtin_amdgcn_s_setprio(0);
    }
  };

  const int nt = 32;  // K/64
  STAGE(0, 0); STAGE(1, 1);
  for (int tt = 0; tt < nt; ++tt) {
    if (tt < nt - 1) asm volatile("s_waitcnt vmcnt(8)" ::: "memory");
    else             asm volatile("s_waitcnt vmcnt(0)" ::: "memory");
    __builtin_amdgcn_s_barrier();
    __builtin_amdgcn_sched_barrier(0);
    COMPUTE(tt & 1);
    __builtin_amdgcn_s_barrier();
    if (tt + 2 < nt) STAGE(tt + 2, tt & 1);
  }
  __builtin_amdgcn_sched_barrier(0);

  int rl0 = wr * 64 + ((lane >> 4) << 2);
  int cl0 = wc * 64 + (lane & 15);
  int r0 = blockIdx.x * 128 + rl0;
  int c0 = blockIdx.y * 128 + cl0;

  bf16_t* Ct = HnT + cz * N2;
  const bf16_t* Hb2 = Hb2T + cz * N2;
  float dj[4], m1v[4];
#pragma unroll
  for (int n = 0; n < 4; ++n) {
    dj[n] = dinv[cz * NN + c0 + n * 16];
    m1v[n] = m1[cz * NN + c0 + n * 16];
  }

  // ---- fused deg2/Mdiag partials (this block's col-range contribution) ----
  float pdeg[4][4], pmd[4][4];
#pragma unroll
  for (int m = 0; m < 4; ++m)
#pragma unroll
    for (int j = 0; j < 4; ++j) {
      int r = r0 + m * 16 + j;
      const bf16_t* hrow = Hb2 + (long long)r * NN;
      float ad = 0.f, am = 0.f;
#pragma unroll
      for (int n = 0; n < 4; ++n) {
        int col = c0 + n * 16;
        float hv = (r == col) ? 0.f : (float)(bf16_t)(acc[m][n][j] * dj[n]);
        float hb = (float)hrow[col];
        am += hv * hb;
        ad += (m1v[n] - hv) * hb;
      }
      pdeg[m][j] = ad; pmd[m][j] = am;
    }
#pragma unroll
  for (int m = 0; m < 4; ++m)
#pragma unroll
    for (int j = 0; j < 4; ++j) {
#pragma unroll
      for (int msk = 1; msk <= 8; msk <<= 1) {
        pdeg[m][j] += __shfl_xor(pdeg[m][j], msk, 64);
        pmd[m][j]  += __shfl_xor(pmd[m][j], msk, 64);
      }
    }
  if ((lane & 15) == 0) {
#pragma unroll
    for (int m = 0; m < 4; ++m)
#pragma unroll
      for (int j = 0; j < 4; ++j) {
        int lrw = m * 16 + ((lane >> 4) << 2) + j;
        sbd[wid * 64 + lrw] = pdeg[m][j];
        sbm[wid * 64 + lrw] = pmd[m][j];
      }
  }
  __syncthreads();
  if (t < 128) {
    int wrof = t >> 6, lr6 = t & 63;
    float dsum = sbd[(wrof * 2 + 0) * 64 + lr6] + sbd[(wrof * 2 + 1) * 64 + lr6];
    float msum = sbm[(wrof * 2 + 0) * 64 + lr6] + sbm[(wrof * 2 + 1) * 64 + lr6];
    long long r = (long long)blockIdx.x * 128 + t;
    pd[((long long)blockIdx.y * CC + cz) * NN + r] = dsum;
    pm[((long long)blockIdx.y * CC + cz) * NN + r] = msum;
  }

  // ---- HnT via LDS transpose (Hn row-major never materialized) ----
#pragma unroll
  for (int m = 0; m < 4; ++m)
#pragma unroll
    for (int n = 0; n < 4; ++n)
#pragma unroll
      for (int j = 0; j < 4; ++j) {
        int r = r0 + m * 16 + j, col = c0 + n * 16;
        float v = (r == col) ? 0.f : acc[m][n][j] * dj[n];
        tile[(rl0 + m * 16 + j) * 130 + cl0 + n * 16] = (bf16_t)v;
      }
  __syncthreads();
  int nl = t >> 5, rl = (t & 31) * 4;
#pragma unroll
  for (int vv = 0; vv < 16; ++vv) {
    int n_l = nl + vv * 8;
    bf16x4 o;
    o[0] = tile[(rl + 0) * 130 + n_l]; o[1] = tile[(rl + 1) * 130 + n_l];
    o[2] = tile[(rl + 2) * 130 + n_l]; o[3] = tile[(rl + 3) * 130 + n_l];
    *(bf16x4*)&Ct[(long long)(blockIdx.y * 128 + n_l) * NN + blockIdx.x * 128 + rl] = o;
  }
}

// ---------------- bf16 GEMM, 128x64 tile, ring-3, counted vmcnt, swizzle, fused epilogues ----------------

enum { EP_BRELU = 3, EP_BF32 = 4, EP_BF16O = 7, EP_XWDT = 8, EP_GCN = 9 };

template<int EP>
__global__ __launch_bounds__(256)
void k_gemm(const bf16_t* __restrict__ A, const bf16_t* __restrict__ B,
            void* __restrict__ Cv,
            const float* __restrict__ aux1, const float* __restrict__ aux2,
            bf16_t* __restrict__ aux3, const float* __restrict__ aux4,
            int N, int K, int lda, int ldb,
            long long zA, long long zB, long long zC) {
  __shared__ __align__(16) char smem[36864];
  bf16_t* As = (bf16_t*)smem;
  bf16_t* Bs = (bf16_t*)(smem + 24576);
  bf16_t* tile = (bf16_t*)smem;

  int cz = blockIdx.z;
  const bf16_t* Ab = A + cz * zA + (long long)blockIdx.x * 128 * lda;
  const bf16_t* Bb = B + cz * zB + (long long)blockIdx.y * 64 * ldb;

  int t = threadIdx.x, wid = t >> 6, lane = t & 63;
  int wr = wid >> 1, wc = wid & 1;
  f32x4 acc[4][2] = {};
  int frow = lane & 15;
  int fk_sw = (((lane >> 4) ^ ((frow >> 1) & 3)) << 3);
  int srow = t >> 2;
  int scol_sw = (((t & 3) ^ ((t >> 3) & 3)) << 3);
  int nt = K >> 5;

  auto STAGE = [&](int TT, int BUF) {
    long long kko = (long long)TT * 32 + scol_sw;
    const bf16_t* ga0 = Ab + (long long)srow * lda + kko;
    const bf16_t* ga1 = Ab + (long long)(64 + srow) * lda + kko;
    const bf16_t* gb0 = Bb + (long long)srow * ldb + kko;
    char* la = smem + BUF * 8192 + wid * 1024;
    char* lb = smem + 24576 + BUF * 4096 + wid * 1024;
    __builtin_amdgcn_global_load_lds((AS1 void*)ga0, (AS3 void*)la, 16, 0, 0);
    __builtin_amdgcn_global_load_lds((AS1 void*)ga1, (AS3 void*)(la + 4096), 16, 0, 0);
    __builtin_amdgcn_global_load_lds((AS1 void*)gb0, (AS3 void*)lb, 16, 0, 0);
  };
  auto COMPUTE = [&](int BUF) {
    bf16x8 af[4], bfr[2];
#pragma unroll
    for (int m = 0; m < 4; ++m)
      af[m] = *(const bf16x8*)&As[BUF * 4096 + (wr * 64 + m * 16 + frow) * 32 + fk_sw];
#pragma unroll
    for (int n = 0; n < 2; ++n)
      bfr[n] = *(const bf16x8*)&Bs[BUF * 2048 + (wc * 32 + n * 16 + frow) * 32 + fk_sw];
#pragma unroll
    for (int m = 0; m < 4; ++m)
#pragma unroll
      for (int n = 0; n < 2; ++n)
        acc[m][n] = __builtin_amdgcn_mfma_f32_16x16x32_bf16(af[m], bfr[n], acc[m][n], 0, 0, 0);
  };

  STAGE(0, 0); STAGE(1, 1); STAGE(2, 2);
  int slot = 0;
  for (int tt = 0; tt < nt; ++tt) {
    int rem = nt - 1 - tt;
    if (rem >= 2)      asm volatile("s_waitcnt vmcnt(6)" ::: "memory");
    else if (rem == 1) asm volatile("s_waitcnt vmcnt(3)" ::: "memory");
    else               asm volatile("s_waitcnt vmcnt(0)" ::: "memory");
    __builtin_amdgcn_s_barrier();
    __builtin_amdgcn_sched_barrier(0);
    COMPUTE(slot);
    __builtin_amdgcn_s_barrier();
    if (tt + 3 < nt) STAGE(tt + 3, slot);
    slot = (slot == 2) ? 0 : slot + 1;
  }
  __builtin_amdgcn_sched_barrier(0);

  int rl0 = wr * 64 + ((lane >> 4) << 2);
  int cl0 = wc * 32 + (lane & 15);
  int r0 = blockIdx.x * 128 + rl0;
  int c0 = blockIdx.y * 64 + cl0;

  if constexpr (EP == EP_BF16O) {
    bf16_t* Cb = (bf16_t*)Cv + cz * zC;
#pragma unroll
    for (int m = 0; m < 4; ++m)
#pragma unroll
      for (int n = 0; n < 2; ++n)
#pragma unroll
        for (int j = 0; j < 4; ++j)
          Cb[(long long)(r0 + m * 16 + j) * N + c0 + n * 16] = (bf16_t)acc[m][n][j];
  } else if constexpr (EP == EP_XWDT) {
    float* Cb = (float*)Cv;
#pragma unroll
    for (int m = 0; m < 4; ++m)
#pragma unroll
      for (int n = 0; n < 2; ++n)
#pragma unroll
        for (int j = 0; j < 4; ++j) {
          float v = acc[m][n][j];
          Cb[(long long)(r0 + m * 16 + j) * N + c0 + n * 16] = v;
          tile[(rl0 + m * 16 + j) * 65 + cl0 + n * 16] = (bf16_t)v;
        }
    __syncthreads();
    int nl = t >> 5, rl = (t & 31) * 4;
#pragma unroll
    for (int vv = 0; vv < 8; ++vv) {
      int n_l = nl + vv * 8;
      bf16x4 v4;
      v4[0] = tile[(rl + 0) * 65 + n_l]; v4[1] = tile[(rl + 1) * 65 + n_l];
      v4[2] = tile[(rl + 2) * 65 + n_l]; v4[3] = tile[(rl + 3) * 65 + n_l];
      int i0 = blockIdx.x * 128 + rl;
      long long row = (long long)(blockIdx.y * 64 + n_l) * NN + i0;
#pragma unroll
      for (int c = 0; c < 2; ++c) {
        float4 dv = *(const float4*)&aux2[c * NN + i0];  // disv
        bf16x4 o;
        o[0] = (bf16_t)((float)v4[0] * dv.x); o[1] = (bf16_t)((float)v4[1] * dv.y);
        o[2] = (bf16_t)((float)v4[2] * dv.z); o[3] = (bf16_t)((float)v4[3] * dv.w);
        *(bf16x4*)&aux3[(long long)c * WOUT * NN + row] = o;
      }
    }
  } else if constexpr (EP == EP_GCN) {
    bf16_t* Cb = (bf16_t*)Cv;
    const float* XWp = aux1;
    const float* csp = aux2 + cz * NN;
    const float* dnp = aux2 + CC * NN + cz * NN;
    const float* mdp = aux2 + 2 * CC * NN + cz * NN;
    float bj[2];
#pragma unroll
    for (int n = 0; n < 2; ++n) bj[n] = aux4[c0 + n * 16];
#pragma unroll
    for (int m = 0; m < 4; ++m)
#pragma unroll
      for (int j = 0; j < 4; ++j) {
        int r = r0 + m * 16 + j;
        float csv = csp[r], dnv = dnp[r], mdv = mdp[r];
        float mdd = mdv * dnv, d2 = dnv * dnv;
#pragma unroll
        for (int n = 0; n < 2; ++n) {
          float xw = XWp[(long long)r * WOUT + c0 + n * 16];
          float v = fmaxf(csv * (acc[m][n][j] - mdd * xw) + d2 * xw + bj[n], 0.f);
          Cb[(long long)r * (CC * WOUT) + cz * WOUT + c0 + n * 16] = (bf16_t)v;
        }
      }
  } else if constexpr (EP == EP_BRELU) {
    bf16_t* Cb = (bf16_t*)Cv;
    float bj[2];
#pragma unroll
    for (int n = 0; n < 2; ++n) bj[n] = aux1[c0 + n * 16];
#pragma unroll
    for (int m = 0; m < 4; ++m)
#pragma unroll
      for (int n = 0; n < 2; ++n)
#pragma unroll
        for (int j = 0; j < 4; ++j)
          Cb[(long long)(r0 + m * 16 + j) * N + c0 + n * 16] =
              (bf16_t)fmaxf(acc[m][n][j] + bj[n], 0.f);
  } else { // EP_BF32
    float* Cb = (float*)Cv;
    float bj[2];
#pragma unroll
    for (int n = 0; n < 2; ++n) bj[n] = aux1[c0 + n * 16];
#pragma unroll
    for (int m = 0; m < 4; ++m)
#pragma unroll
      for (int n = 0; n < 2; ++n)
#pragma unroll
        for (int j = 0; j < 4; ++j)
          Cb[(long long)(r0 + m * 16 + j) * N + c0 + n * 16] = acc[m][n][j] + bj[n];
  }
}

// ---------------- launch ----------------

extern "C" void kernel_launch(void* const* d_in, const int* in_sizes, int n_in,
                              void* d_out, int out_size, void* d_ws, size_t ws_size,
                              hipStream_t stream) {
  const float* A    = (const float*)d_in[0];
  const float* X    = (const float*)d_in[1];
  const float* w0a  = (const float*)d_in[2];
  const float* w0b  = (const float*)d_in[3];
  const float* w1   = (const float*)d_in[4];
  const float* gcnw = (const float*)d_in[5];
  const float* gcnb = (const float*)d_in[6];
  const float* l1w  = (const float*)d_in[7];
  const float* l1b  = (const float*)d_in[8];
  const float* l2w  = (const float*)d_in[9];
  const float* l2b  = (const float*)d_in[10];
  float* out = (float*)d_out;

  char* p = (char*)d_ws;
  auto carve = [&](size_t bytes) -> char* {
    char* r = p; p += (bytes + 255) & ~(size_t)255; return r;
  };
  float*  svec  = (float*)carve((size_t)CC * NN * 4);
  float*  dinv1 = (float*)carve((size_t)CC * NN * 4);
  float*  m1    = (float*)carve((size_t)CC * NN * 4);
  float*  scal  = (float*)carve((size_t)3 * CC * NN * 4);   // cscal | disv | Mdiag
  float*  part  = (float*)carve((size_t)CC * 32 * NN * 4);
  float*  pd    = (float*)carve((size_t)16 * CC * NN * 4);  // deg2 partials per by
  float*  pmg   = (float*)carve((size_t)16 * CC * NN * 4);  // Mdiag partials per by
  bf16_t* S1    = (bf16_t*)carve((size_t)CC * N2 * 2);  // Ha -> {XWdT, Yt}
  bf16_t* HbT   = (bf16_t*)carve((size_t)CC * N2 * 2);
  bf16_t* Hb2T  = (bf16_t*)carve((size_t)CC * N2 * 2);
  bf16_t* HnT   = (bf16_t*)carve((size_t)CC * N2 * 2);
  bf16_t* Xb    = (bf16_t*)carve((size_t)NN * WIN * 2);
  bf16_t* gwT   = (bf16_t*)carve((size_t)WOUT * WIN * 2);
  bf16_t* l1wb  = (bf16_t*)carve((size_t)WOUT * CC * WOUT * 2);
  bf16_t* l2wb  = (bf16_t*)carve((size_t)WOUT * WOUT * 2);
  float*  XW    = (float*)carve((size_t)NN * WOUT * 4);
  bf16_t* Xcat  = (bf16_t*)carve((size_t)NN * CC * WOUT * 2);
  bf16_t* hb    = (bf16_t*)carve((size_t)NN * WOUT * 2);

  bf16_t* Ha = S1;
  bf16_t* XWdT = (bf16_t*)((char*)S1);                 // 2 MB (Ha dead after gemmL)
  bf16_t* Yt   = (bf16_t*)((char*)S1 + (2LL << 20));   // 2 MB
  float*  disv = scal + CC * NN;

  // combine (+merged prep)
  k_combine<<<1664, 256, 0, stream>>>(A, w0a, w0b, w1, Ha, HbT, Hb2T, part,
                                      X, l1w, l2w, gcnw, Xb, l1wb, l2wb, gwT);
  k_s_finish<<<16, 256, 0, stream>>>(part, svec);

  // layer 0 scalars, then GEMM1 with fused normalize -> HnT + deg2/Mdiag partials
  k_deg1<<<dim3(512, 2), 256, 0, stream>>>(svec, Ha, HbT, dinv1, m1);
  k_gemmL<<<dim3(16, 16, 2), 256, 0, stream>>>(Ha, HbT, HnT, dinv1, m1, Hb2T, pd, pmg);
  k_deg2_finish<<<16, 256, 0, stream>>>(pd, pmg, scal);

  // GCN via associativity: XW (+fused disv-scaled transpose -> XWdT both channels);
  // Yt = XWdT @ HnT^T; Xcat = gcn-epilogue(Hb2T @ Yt^T)
  k_gemm<EP_XWDT><<<dim3(16, 4, 1), 256, 0, stream>>>(
      Xb, gwT, XW, nullptr, disv, XWdT, nullptr, WOUT, WIN, WIN, WIN, 0, 0, 0);
  k_gemm<EP_BF16O><<<dim3(2, 32, 2), 256, 0, stream>>>(
      XWdT, HnT, Yt, nullptr, nullptr, nullptr, nullptr, NN, NN, NN, NN,
      (long long)WOUT * NN, N2, (long long)WOUT * NN);
  k_gemm<EP_GCN><<<dim3(16, 4, 2), 256, 0, stream>>>(
      Hb2T, Yt, Xcat, XW, scal, nullptr, gcnb, WOUT, NN, NN, NN,
      N2, (long long)WOUT * NN, 0);

  // MLP with fused bias(+relu)
  k_gemm<EP_BRELU><<<dim3(16, 4, 1), 256, 0, stream>>>(
      Xcat, l1wb, hb, l1b, nullptr, nullptr, nullptr, WOUT, CC * WOUT, CC * WOUT, CC * WOUT, 0, 0, 0);
  k_gemm<EP_BF32><<<dim3(16, 4, 1), 256, 0, stream>>>(
      hb, l2wb, out, l2b, nullptr, nullptr, nullptr, WOUT, WOUT, WOUT, WOUT, 0, 0, 0);
}

// Round 15
// 134.471 us; speedup vs baseline: 1.2261x; 1.0503x over previous
//
#include <hip/hip_runtime.h>
#include <cstdint>
#include <cstddef>

#define NN   2048
#define N2   (2048LL*2048LL)
#define CC   2
#define EE   5
#define WIN  512
#define WOUT 256

typedef __bf16 bf16_t;
typedef __attribute__((ext_vector_type(8))) __bf16 bf16x8;
typedef __attribute__((ext_vector_type(4))) __bf16 bf16x4;
typedef __attribute__((ext_vector_type(4))) float  f32x4;

#define AS1 __attribute__((address_space(1)))
#define AS3 __attribute__((address_space(3)))

// ---------------- combine (+merged prep): single A pass, prefetch-pipelined loads ----------------

__global__ __launch_bounds__(256, 2)
void k_combine(const float* __restrict__ A,
               const float* __restrict__ w0a, const float* __restrict__ w0b,
               const float* __restrict__ w1,
               bf16_t* __restrict__ Ha, bf16_t* __restrict__ HbT,
               bf16_t* __restrict__ Hb2T, float* __restrict__ part,
               const float* __restrict__ X, const float* __restrict__ l1w,
               const float* __restrict__ l2w, const float* __restrict__ gcnw,
               bf16_t* __restrict__ Xb, bf16_t* __restrict__ l1wb,
               bf16_t* __restrict__ l2wb, bf16_t* __restrict__ gwT) {
  __shared__ bf16_t tl[2][64][65];
  __shared__ float cs[2][4][64];
  int bid = blockIdx.x;
  int t = threadIdx.x;

  if (bid >= 1024) {
    int bid2 = bid - 1024;
    if (bid2 < 608) {
      int i = bid2 * 256 + t;
      const float* src; bf16_t* dst; int off;
      if (i < 131072)      { src = X;   dst = Xb;   off = i; }
      else if (i < 147456) { src = l1w; dst = l1wb; off = i - 131072; }
      else                 { src = l2w; dst = l2wb; off = i - 147456; }
      float4 a = ((const float4*)src)[off * 2];
      float4 b = ((const float4*)src)[off * 2 + 1];
      bf16x8 o;
      o[0] = (bf16_t)a.x; o[1] = (bf16_t)a.y; o[2] = (bf16_t)a.z; o[3] = (bf16_t)a.w;
      o[4] = (bf16_t)b.x; o[5] = (bf16_t)b.y; o[6] = (bf16_t)b.z; o[7] = (bf16_t)b.w;
      ((bf16x8*)dst)[off] = o;
    } else {
      int b2 = bid2 - 608;
      int m0 = (b2 & 7) * 64, n0 = (b2 >> 3) * 64;
      int tr = t >> 4, tc = (t & 15) << 2;
      bf16_t (*tile)[65] = (bf16_t (*)[65])&tl[0][0][0];
#pragma unroll
      for (int v = 0; v < 4; ++v) {
        int r = tr + v * 16;
        float4 d = *(const float4*)&gcnw[(long long)(m0 + r) * WOUT + n0 + tc];
        tile[r][tc + 0] = (bf16_t)d.x; tile[r][tc + 1] = (bf16_t)d.y;
        tile[r][tc + 2] = (bf16_t)d.z; tile[r][tc + 3] = (bf16_t)d.w;
      }
      __syncthreads();
#pragma unroll
      for (int v = 0; v < 4; ++v) {
        int r = tr + v * 16;
        bf16x4 o;
        o[0] = tile[tc + 0][r]; o[1] = tile[tc + 1][r];
        o[2] = tile[tc + 2][r]; o[3] = tile[tc + 3][r];
        *(bf16x4*)&gwT[(long long)(n0 + r) * WIN + m0 + tc] = o;
      }
    }
    return;
  }

  float f[3][2][5];
  {
    const float* wp[3] = {w0a, w0b, w1};
#pragma unroll
    for (int w = 0; w < 3; ++w)
#pragma unroll
      for (int c = 0; c < 2; ++c) {
        float x[5], m = -1e30f, s = 0.f;
#pragma unroll
        for (int e = 0; e < 5; ++e) { x[e] = wp[w][c * 5 + e]; m = fmaxf(m, x[e]); }
#pragma unroll
        for (int e = 0; e < 5; ++e) { x[e] = expf(x[e] - m); s += x[e]; }
#pragma unroll
        for (int e = 0; e < 5; ++e) f[w][c][e] = x[e] / s;
      }
  }
  int i0 = (bid >> 5) * 64, j0 = (bid & 31) * 64;
  int tr = t >> 4, tc = (t & 15) << 2;
  int lane = t & 63, wid = t >> 6;
  float cs0[4] = {0, 0, 0, 0}, cs1[4] = {0, 0, 0, 0};
  bf16x4 hb2a[4], hb2b[4];

  float4 q[5];
  {
    const float* b0 = A + (long long)(i0 + tr) * NN + j0 + tc;
#pragma unroll
    for (int e = 0; e < 5; ++e) q[e] = *(const float4*)(b0 + (long long)e * N2);
  }
#pragma unroll
  for (int v = 0; v < 4; ++v) {
    int lr = tr + v * 16;
    long long gi = i0 + lr;
    float av[5][4];
#pragma unroll
    for (int e = 0; e < 5; ++e) {
      av[e][0] = q[e].x; av[e][1] = q[e].y; av[e][2] = q[e].z; av[e][3] = q[e].w;
    }
    if (v < 3) {
      const float* bn = A + (gi + 16) * (long long)NN + j0 + tc;
#pragma unroll
      for (int e = 0; e < 5; ++e) q[e] = *(const float4*)(bn + (long long)e * N2);
    }
    bf16x4 ha0, ha1;
#pragma unroll
    for (int x = 0; x < 4; ++x) {
      float s0 = 0.f, s1 = 0.f, s2 = 0.f, s3 = 0.f, s4 = 0.f, s5 = 0.f;
#pragma unroll
      for (int e = 0; e < 5; ++e) {
        float u = av[e][x];
        s0 += f[0][0][e] * u; s1 += f[0][1][e] * u;
        s2 += f[1][0][e] * u; s3 += f[1][1][e] * u;
        s4 += f[2][0][e] * u; s5 += f[2][1][e] * u;
      }
      ha0[x] = (bf16_t)s0; cs0[x] += (float)ha0[x];
      ha1[x] = (bf16_t)s1; cs1[x] += (float)ha1[x];
      tl[0][lr][tc + x] = (bf16_t)s2; tl[1][lr][tc + x] = (bf16_t)s3;
      hb2a[v][x] = (bf16_t)s4; hb2b[v][x] = (bf16_t)s5;
    }
    *(bf16x4*)&Ha[0 * N2 + gi * NN + j0 + tc] = ha0;
    *(bf16x4*)&Ha[1 * N2 + gi * NN + j0 + tc] = ha1;
  }
#pragma unroll
  for (int x = 0; x < 4; ++x) {
    float a0 = cs0[x], a1 = cs1[x];
    a0 += __shfl_xor(a0, 16, 64); a0 += __shfl_xor(a0, 32, 64);
    a1 += __shfl_xor(a1, 16, 64); a1 += __shfl_xor(a1, 32, 64);
    if ((lane >> 4) == 0) {
      cs[0][wid][(lane & 15) * 4 + x] = a0;
      cs[1][wid][(lane & 15) * 4 + x] = a1;
    }
  }
  __syncthreads();

#pragma unroll
  for (int v = 0; v < 4; ++v) {
    int lr = tr + v * 16;
#pragma unroll
    for (int ch = 0; ch < 2; ++ch) {
      bf16x4 o;
      o[0] = tl[ch][tc + 0][lr]; o[1] = tl[ch][tc + 1][lr];
      o[2] = tl[ch][tc + 2][lr]; o[3] = tl[ch][tc + 3][lr];
      *(bf16x4*)&HbT[(long long)ch * N2 + (long long)(j0 + lr) * NN + i0 + tc] = o;
    }
  }
  if (t < 128) {
    int ch = t >> 6, col = t & 63;
    float s = cs[ch][0][col] + cs[ch][1][col] + cs[ch][2][col] + cs[ch][3][col];
    part[((long long)ch * 32 + (bid >> 5)) * NN + j0 + col] = s;
  }
  __syncthreads();

#pragma unroll
  for (int v = 0; v < 4; ++v) {
    int lr = tr + v * 16;
#pragma unroll
    for (int x = 0; x < 4; ++x) {
      tl[0][lr][tc + x] = hb2a[v][x];
      tl[1][lr][tc + x] = hb2b[v][x];
    }
  }
  __syncthreads();

#pragma unroll
  for (int v = 0; v < 4; ++v) {
    int lr = tr + v * 16;
#pragma unroll
    for (int ch = 0; ch < 2; ++ch) {
      bf16x4 o;
      o[0] = tl[ch][tc + 0][lr]; o[1] = tl[ch][tc + 1][lr];
      o[2] = tl[ch][tc + 2][lr]; o[3] = tl[ch][tc + 3][lr];
      *(bf16x4*)&Hb2T[(long long)ch * N2 + (long long)(j0 + lr) * NN + i0 + tc] = o;
    }
  }
}

__global__ void k_s_finish(const float* __restrict__ part, float* __restrict__ s) {
  int idx = blockIdx.x * 256 + threadIdx.x;
  int c = idx >> 11, k = idx & 2047;
  float acc = 0.f;
#pragma unroll
  for (int ib = 0; ib < 32; ++ib) acc += part[((long long)c * 32 + ib) * NN + k];
  s[idx] = acc;
}

// deg1[c][j] = sum_k (svec[k] - Ha[j,k])*HbT[j,k]  -> dinv1, m1
__global__ void k_deg1(const float* __restrict__ svec, const bf16_t* __restrict__ Arows,
                       const bf16_t* __restrict__ BT,
                       float* __restrict__ out1, float* __restrict__ out2) {
  int c = blockIdx.y;
  int j = blockIdx.x * 4 + (threadIdx.x >> 6);
  int lane = threadIdx.x & 63;
  const bf16_t* a = Arows + (long long)c * N2 + (long long)j * NN;
  const bf16_t* b = BT + (long long)c * N2 + (long long)j * NN;
  const float* s = svec + c * NN;
  float acc_s = 0.f, acc_a = 0.f;
#pragma unroll
  for (int it = 0; it < 4; ++it) {
    int k0 = (lane + it * 64) * 8;
    bf16x8 av = *(const bf16x8*)(a + k0);
    bf16x8 bv = *(const bf16x8*)(b + k0);
    float4 s0 = *(const float4*)(s + k0);
    float4 s1 = *(const float4*)(s + k0 + 4);
    float sv[8] = {s0.x, s0.y, s0.z, s0.w, s1.x, s1.y, s1.z, s1.w};
#pragma unroll
    for (int x = 0; x < 8; ++x) {
      float bx = (float)bv[x];
      acc_s += sv[x] * bx;
      acc_a += (float)av[x] * bx;
    }
  }
#pragma unroll
  for (int o = 32; o > 0; o >>= 1) {
    acc_s += __shfl_xor(acc_s, o, 64);
    acc_a += __shfl_xor(acc_a, o, 64);
  }
  if (lane == 0) {
    float deg = acc_s - acc_a;
    bool nz = (deg != 0.f);
    out1[c * NN + j] = nz ? 1.f / deg : 0.f;
    out2[c * NN + j] = nz ? 1.f : 0.f;
  }
}

__global__ void k_deg2_finish(const float* __restrict__ pd, const float* __restrict__ pm,
                              float* __restrict__ scal) {
  int idx = blockIdx.x * 256 + threadIdx.x;
  int c = idx >> 11, r = idx & 2047;
  float deg = 0.f, md = 0.f;
#pragma unroll
  for (int by = 0; by < 16; ++by) {
    deg += pd[((long long)by * CC + c) * NN + r];
    md  += pm[((long long)by * CC + c) * NN + r];
  }
  bool nz = (deg != 0.f);
  float dis = nz ? 0.70710678118654752f : 1.f;
  scal[c * NN + r] = nz ? dis / deg : 0.f;
  scal[CC * NN + c * NN + r] = dis;
  scal[2 * CC * NN + c * NN + r] = md;
}

// ---------------- GEMM1: 128x128 tile, BK=64 ring-2; epilogue emits HnT + deg2/Mdiag partials ----------------

__global__ __launch_bounds__(256)
void k_gemmL(const bf16_t* __restrict__ A, const bf16_t* __restrict__ B,
             bf16_t* __restrict__ HnT, const float* __restrict__ dinv,
             const float* __restrict__ m1, const bf16_t* __restrict__ Hb2T,
             float* __restrict__ pd, float* __restrict__ pm) {
  __shared__ __align__(16) char smem[65536];
  bf16_t* As = (bf16_t*)smem;
  bf16_t* Bs = (bf16_t*)(smem + 32768);
  bf16_t* tile = (bf16_t*)smem;
  float* sbd = (float*)(smem + 34816);
  float* sbm = (float*)(smem + 34816 + 1024);

  int cz = blockIdx.z;
  const bf16_t* Ab = A + cz * N2 + (long long)blockIdx.x * 128 * NN;
  const bf16_t* Bb = B + cz * N2 + (long long)blockIdx.y * 128 * NN;

  int t = threadIdx.x, wid = t >> 6, lane = t & 63;
  int wr = wid >> 1, wc = wid & 1;
  f32x4 acc[4][4] = {};
  int frow = lane & 15;
  int fk_sw = (((lane >> 4) ^ ((frow >> 1) & 3)) << 3);
  int srow = t >> 2;
  int scol_sw = (((t & 3) ^ ((t >> 3) & 3)) << 3);

  auto STAGE = [&](int TT, int BUF) {
#pragma unroll
    for (int s = 0; s < 2; ++s) {
      long long kko = (long long)TT * 64 + s * 32 + scol_sw;
      const bf16_t* ga0 = Ab + (long long)srow * NN + kko;
      const bf16_t* gb0 = Bb + (long long)srow * NN + kko;
      char* la = smem + BUF * 16384 + s * 8192 + wid * 1024;
      char* lb = smem + 32768 + BUF * 16384 + s * 8192 + wid * 1024;
      __builtin_amdgcn_global_load_lds((AS1 void*)ga0, (AS3 void*)la, 16, 0, 0);
      __builtin_amdgcn_global_load_lds((AS1 void*)(ga0 + 64LL * NN), (AS3 void*)(la + 4096), 16, 0, 0);
      __builtin_amdgcn_global_load_lds((AS1 void*)gb0, (AS3 void*)lb, 16, 0, 0);
      __builtin_amdgcn_global_load_lds((AS1 void*)(gb0 + 64LL * NN), (AS3 void*)(lb + 4096), 16, 0, 0);
    }
  };
  auto COMPUTE = [&](int BUF) {
#pragma unroll
    for (int ks = 0; ks < 2; ++ks) {
      bf16x8 af[4], bfr[4];
#pragma unroll
      for (int m = 0; m < 4; ++m)
        af[m] = *(const bf16x8*)&As[BUF * 8192 + ks * 4096 + (wr * 64 + m * 16 + frow) * 32 + fk_sw];
#pragma unroll
      for (int n = 0; n < 4; ++n)
        bfr[n] = *(const bf16x8*)&Bs[BUF * 8192 + ks * 4096 + (wc * 64 + n * 16 + frow) * 32 + fk_sw];
      __builtin_amdgcn_s_setprio(1);
#pragma unroll
      for (int m = 0; m < 4; ++m)
#pragma unroll
        for (int n = 0; n < 4; ++n)
          acc[m][n] = __builtin_amdgcn_mfma_f32_16x16x32_bf16(af[m], bfr[n], acc[m][n], 0, 0, 0);
      __builtin_amdgcn_s_setprio(0);
    }
  };

  const int nt = 32;
  STAGE(0, 0); STAGE(1, 1);
  for (int tt = 0; tt < nt; ++tt) {
    if (tt < nt - 1) asm volatile("s_waitcnt vmcnt(8)" ::: "memory");
    else             asm volatile("s_waitcnt vmcnt(0)" ::: "memory");
    __builtin_amdgcn_s_barrier();
    __builtin_amdgcn_sched_barrier(0);
    COMPUTE(tt & 1);
    __builtin_amdgcn_s_barrier();
    if (tt + 2 < nt) STAGE(tt + 2, tt & 1);
  }
  __builtin_amdgcn_sched_barrier(0);

  int rl0 = wr * 64 + ((lane >> 4) << 2);
  int cl0 = wc * 64 + (lane & 15);
  int r0 = blockIdx.x * 128 + rl0;
  int c0 = blockIdx.y * 128 + cl0;

  bf16_t* Ct = HnT + cz * N2;
  const bf16_t* Hb2 = Hb2T + cz * N2;
  float dj[4], m1v[4];
#pragma unroll
  for (int n = 0; n < 4; ++n) {
    dj[n] = dinv[cz * NN + c0 + n * 16];
    m1v[n] = m1[cz * NN + c0 + n * 16];
  }

  float pdeg[4][4], pmd[4][4];
#pragma unroll
  for (int m = 0; m < 4; ++m)
#pragma unroll
    for (int j = 0; j < 4; ++j) {
      int r = r0 + m * 16 + j;
      const bf16_t* hrow = Hb2 + (long long)r * NN;
      float ad = 0.f, am = 0.f;
#pragma unroll
      for (int n = 0; n < 4; ++n) {
        int col = c0 + n * 16;
        float hv = (r == col) ? 0.f : (float)(bf16_t)(acc[m][n][j] * dj[n]);
        float hb = (float)hrow[col];
        am += hv * hb;
        ad += (m1v[n] - hv) * hb;
      }
      pdeg[m][j] = ad; pmd[m][j] = am;
    }
#pragma unroll
  for (int m = 0; m < 4; ++m)
#pragma unroll
    for (int j = 0; j < 4; ++j) {
#pragma unroll
      for (int msk = 1; msk <= 8; msk <<= 1) {
        pdeg[m][j] += __shfl_xor(pdeg[m][j], msk, 64);
        pmd[m][j]  += __shfl_xor(pmd[m][j], msk, 64);
      }
    }
  if ((lane & 15) == 0) {
#pragma unroll
    for (int m = 0; m < 4; ++m)
#pragma unroll
      for (int j = 0; j < 4; ++j) {
        int lrw = m * 16 + ((lane >> 4) << 2) + j;
        sbd[wid * 64 + lrw] = pdeg[m][j];
        sbm[wid * 64 + lrw] = pmd[m][j];
      }
  }
  __syncthreads();
  if (t < 128) {
    int wrof = t >> 6, lr6 = t & 63;
    float dsum = sbd[(wrof * 2 + 0) * 64 + lr6] + sbd[(wrof * 2 + 1) * 64 + lr6];
    float msum = sbm[(wrof * 2 + 0) * 64 + lr6] + sbm[(wrof * 2 + 1) * 64 + lr6];
    long long r = (long long)blockIdx.x * 128 + t;
    pd[((long long)blockIdx.y * CC + cz) * NN + r] = dsum;
    pm[((long long)blockIdx.y * CC + cz) * NN + r] = msum;
  }

#pragma unroll
  for (int m = 0; m < 4; ++m)
#pragma unroll
    for (int n = 0; n < 4; ++n)
#pragma unroll
      for (int j = 0; j < 4; ++j) {
        int r = r0 + m * 16 + j, col = c0 + n * 16;
        float v = (r == col) ? 0.f : acc[m][n][j] * dj[n];
        tile[(rl0 + m * 16 + j) * 130 + cl0 + n * 16] = (bf16_t)v;
      }
  __syncthreads();
  int nl = t >> 5, rl = (t & 31) * 4;
#pragma unroll
  for (int vv = 0; vv < 16; ++vv) {
    int n_l = nl + vv * 8;
    bf16x4 o;
    o[0] = tile[(rl + 0) * 130 + n_l]; o[1] = tile[(rl + 1) * 130 + n_l];
    o[2] = tile[(rl + 2) * 130 + n_l]; o[3] = tile[(rl + 3) * 130 + n_l];
    *(bf16x4*)&Ct[(long long)(blockIdx.y * 128 + n_l) * NN + blockIdx.x * 128 + rl] = o;
  }
}

// ---------------- bf16 GEMM, BMx64 tile (BM=128 or 64), ring-3, counted vmcnt, swizzle ----------------

enum { EP_BRELU = 3, EP_BF32 = 4, EP_BF16O = 7, EP_XWDT = 8, EP_GCN = 9 };

template<int EP, int BM>
__global__ __launch_bounds__(256)
void k_gemm(const bf16_t* __restrict__ A, const bf16_t* __restrict__ B,
            void* __restrict__ Cv,
            const float* __restrict__ aux1, const float* __restrict__ aux2,
            bf16_t* __restrict__ aux3, const float* __restrict__ aux4,
            int N, int K, int lda, int ldb,
            long long zA, long long zB, long long zC) {
  constexpr int MM = BM / 32;                 // per-wave m-fragments
  constexpr int ASLOT = BM * 64;              // A slot bytes (BM x 32 bf16)
  constexpr int BBASE = 3 * ASLOT;            // Bs base byte offset
  __shared__ __align__(16) char smem[BBASE + 3 * 4096 > 36864 ? BBASE + 3 * 4096 : 36864];
  bf16_t* As = (bf16_t*)smem;
  bf16_t* Bs = (bf16_t*)(smem + BBASE);
  bf16_t* tile = (bf16_t*)smem;

  int cz = blockIdx.z;
  const bf16_t* Ab = A + cz * zA + (long long)blockIdx.x * BM * lda;
  const bf16_t* Bb = B + cz * zB + (long long)blockIdx.y * 64 * ldb;

  int t = threadIdx.x, wid = t >> 6, lane = t & 63;
  int wr = wid >> 1, wc = wid & 1;
  f32x4 acc[MM][2] = {};
  int frow = lane & 15;
  int fk_sw = (((lane >> 4) ^ ((frow >> 1) & 3)) << 3);
  int srow = t >> 2;
  int scol_sw = (((t & 3) ^ ((t >> 3) & 3)) << 3);
  int nt = K >> 5;

  auto STAGE = [&](int TT, int BUF) {
    long long kko = (long long)TT * 32 + scol_sw;
    const bf16_t* ga0 = Ab + (long long)srow * lda + kko;
    const bf16_t* gb0 = Bb + (long long)srow * ldb + kko;
    char* la = smem + BUF * ASLOT + wid * 1024;
    char* lb = smem + BBASE + BUF * 4096 + wid * 1024;
    __builtin_amdgcn_global_load_lds((AS1 void*)ga0, (AS3 void*)la, 16, 0, 0);
    if constexpr (BM == 128)
      __builtin_amdgcn_global_load_lds((AS1 void*)(ga0 + 64LL * lda), (AS3 void*)(la + 4096), 16, 0, 0);
    __builtin_amdgcn_global_load_lds((AS1 void*)gb0, (AS3 void*)lb, 16, 0, 0);
  };
  auto COMPUTE = [&](int BUF) {
    bf16x8 af[MM], bfr[2];
#pragma unroll
    for (int m = 0; m < MM; ++m)
      af[m] = *(const bf16x8*)&As[BUF * (ASLOT / 2) + (wr * (BM / 2) + m * 16 + frow) * 32 + fk_sw];
#pragma unroll
    for (int n = 0; n < 2; ++n)
      bfr[n] = *(const bf16x8*)&Bs[BUF * 2048 + (wc * 32 + n * 16 + frow) * 32 + fk_sw];
#pragma unroll
    for (int m = 0; m < MM; ++m)
#pragma unroll
      for (int n = 0; n < 2; ++n)
        acc[m][n] = __builtin_amdgcn_mfma_f32_16x16x32_bf16(af[m], bfr[n], acc[m][n], 0, 0, 0);
  };

  STAGE(0, 0); STAGE(1, 1); STAGE(2, 2);
  int slot = 0;
  for (int tt = 0; tt < nt; ++tt) {
    int rem = nt - 1 - tt;
    if constexpr (BM == 128) {
      if (rem >= 2)      asm volatile("s_waitcnt vmcnt(6)" ::: "memory");
      else if (rem == 1) asm volatile("s_waitcnt vmcnt(3)" ::: "memory");
      else               asm volatile("s_waitcnt vmcnt(0)" ::: "memory");
    } else {
      if (rem >= 2)      asm volatile("s_waitcnt vmcnt(4)" ::: "memory");
      else if (rem == 1) asm volatile("s_waitcnt vmcnt(2)" ::: "memory");
      else               asm volatile("s_waitcnt vmcnt(0)" ::: "memory");
    }
    __builtin_amdgcn_s_barrier();
    __builtin_amdgcn_sched_barrier(0);
    COMPUTE(slot);
    __builtin_amdgcn_s_barrier();
    if (tt + 3 < nt) STAGE(tt + 3, slot);
    slot = (slot == 2) ? 0 : slot + 1;
  }
  __builtin_amdgcn_sched_barrier(0);

  int rl0 = wr * (BM / 2) + ((lane >> 4) << 2);
  int cl0 = wc * 32 + (lane & 15);
  int r0 = blockIdx.x * BM + rl0;
  int c0 = blockIdx.y * 64 + cl0;

  if constexpr (EP == EP_BF16O) {
    bf16_t* Cb = (bf16_t*)Cv + cz * zC;
#pragma unroll
    for (int m = 0; m < MM; ++m)
#pragma unroll
      for (int n = 0; n < 2; ++n)
#pragma unroll
        for (int j = 0; j < 4; ++j)
          Cb[(long long)(r0 + m * 16 + j) * N + c0 + n * 16] = (bf16_t)acc[m][n][j];
  } else if constexpr (EP == EP_XWDT) {
    float* Cb = (float*)Cv;
#pragma unroll
    for (int m = 0; m < MM; ++m)
#pragma unroll
      for (int n = 0; n < 2; ++n)
#pragma unroll
        for (int j = 0; j < 4; ++j) {
          float v = acc[m][n][j];
          Cb[(long long)(r0 + m * 16 + j) * N + c0 + n * 16] = v;
          tile[(rl0 + m * 16 + j) * 65 + cl0 + n * 16] = (bf16_t)v;
        }
    __syncthreads();
    int nl = t >> 5, rl = (t & 31) * 4;
#pragma unroll
    for (int vv = 0; vv < 8; ++vv) {
      int n_l = nl + vv * 8;
      bf16x4 v4;
      v4[0] = tile[(rl + 0) * 65 + n_l]; v4[1] = tile[(rl + 1) * 65 + n_l];
      v4[2] = tile[(rl + 2) * 65 + n_l]; v4[3] = tile[(rl + 3) * 65 + n_l];
      int i0 = blockIdx.x * BM + rl;
      long long row = (long long)(blockIdx.y * 64 + n_l) * NN + i0;
#pragma unroll
      for (int c = 0; c < 2; ++c) {
        float4 dv = *(const float4*)&aux2[c * NN + i0];  // disv
        bf16x4 o;
        o[0] = (bf16_t)((float)v4[0] * dv.x); o[1] = (bf16_t)((float)v4[1] * dv.y);
        o[2] = (bf16_t)((float)v4[2] * dv.z); o[3] = (bf16_t)((float)v4[3] * dv.w);
        *(bf16x4*)&aux3[(long long)c * WOUT * NN + row] = o;
      }
    }
  } else if constexpr (EP == EP_GCN) {
    bf16_t* Cb = (bf16_t*)Cv;
    const float* XWp = aux1;
    const float* csp = aux2 + cz * NN;
    const float* dnp = aux2 + CC * NN + cz * NN;
    const float* mdp = aux2 + 2 * CC * NN + cz * NN;
    float bj[2];
#pragma unroll
    for (int n = 0; n < 2; ++n) bj[n] = aux4[c0 + n * 16];
#pragma unroll
    for (int m = 0; m < MM; ++m)
#pragma unroll
      for (int j = 0; j < 4; ++j) {
        int r = r0 + m * 16 + j;
        float csv = csp[r], dnv = dnp[r], mdv = mdp[r];
        float mdd = mdv * dnv, d2 = dnv * dnv;
#pragma unroll
        for (int n = 0; n < 2; ++n) {
          float xw = XWp[(long long)r * WOUT + c0 + n * 16];
          float v = fmaxf(csv * (acc[m][n][j] - mdd * xw) + d2 * xw + bj[n], 0.f);
          Cb[(long long)r * (CC * WOUT) + cz * WOUT + c0 + n * 16] = (bf16_t)v;
        }
      }
  } else if constexpr (EP == EP_BRELU) {
    bf16_t* Cb = (bf16_t*)Cv;
    float bj[2];
#pragma unroll
    for (int n = 0; n < 2; ++n) bj[n] = aux1[c0 + n * 16];
#pragma unroll
    for (int m = 0; m < MM; ++m)
#pragma unroll
      for (int n = 0; n < 2; ++n)
#pragma unroll
        for (int j = 0; j < 4; ++j)
          Cb[(long long)(r0 + m * 16 + j) * N + c0 + n * 16] =
              (bf16_t)fmaxf(acc[m][n][j] + bj[n], 0.f);
  } else { // EP_BF32
    float* Cb = (float*)Cv;
    float bj[2];
#pragma unroll
    for (int n = 0; n < 2; ++n) bj[n] = aux1[c0 + n * 16];
#pragma unroll
    for (int m = 0; m < MM; ++m)
#pragma unroll
      for (int n = 0; n < 2; ++n)
#pragma unroll
        for (int j = 0; j < 4; ++j)
          Cb[(long long)(r0 + m * 16 + j) * N + c0 + n * 16] = acc[m][n][j] + bj[n];
  }
}

// ---------------- launch ----------------

extern "C" void kernel_launch(void* const* d_in, const int* in_sizes, int n_in,
                              void* d_out, int out_size, void* d_ws, size_t ws_size,
                              hipStream_t stream) {
  const float* A    = (const float*)d_in[0];
  const float* X    = (const float*)d_in[1];
  const float* w0a  = (const float*)d_in[2];
  const float* w0b  = (const float*)d_in[3];
  const float* w1   = (const float*)d_in[4];
  const float* gcnw = (const float*)d_in[5];
  const float* gcnb = (const float*)d_in[6];
  const float* l1w  = (const float*)d_in[7];
  const float* l1b  = (const float*)d_in[8];
  const float* l2w  = (const float*)d_in[9];
  const float* l2b  = (const float*)d_in[10];
  float* out = (float*)d_out;

  char* p = (char*)d_ws;
  auto carve = [&](size_t bytes) -> char* {
    char* r = p; p += (bytes + 255) & ~(size_t)255; return r;
  };
  float*  svec  = (float*)carve((size_t)CC * NN * 4);
  float*  dinv1 = (float*)carve((size_t)CC * NN * 4);
  float*  m1    = (float*)carve((size_t)CC * NN * 4);
  float*  scal  = (float*)carve((size_t)3 * CC * NN * 4);   // cscal | disv | Mdiag
  float*  part  = (float*)carve((size_t)CC * 32 * NN * 4);
  float*  pd    = (float*)carve((size_t)16 * CC * NN * 4);
  float*  pmg   = (float*)carve((size_t)16 * CC * NN * 4);
  bf16_t* S1    = (bf16_t*)carve((size_t)CC * N2 * 2);  // Ha -> {XWdT, Yt}
  bf16_t* HbT   = (bf16_t*)carve((size_t)CC * N2 * 2);
  bf16_t* Hb2T  = (bf16_t*)carve((size_t)CC * N2 * 2);
  bf16_t* HnT   = (bf16_t*)carve((size_t)CC * N2 * 2);
  bf16_t* Xb    = (bf16_t*)carve((size_t)NN * WIN * 2);
  bf16_t* gwT   = (bf16_t*)carve((size_t)WOUT * WIN * 2);
  bf16_t* l1wb  = (bf16_t*)carve((size_t)WOUT * CC * WOUT * 2);
  bf16_t* l2wb  = (bf16_t*)carve((size_t)WOUT * WOUT * 2);
  float*  XW    = (float*)carve((size_t)NN * WOUT * 4);
  bf16_t* Xcat  = (bf16_t*)carve((size_t)NN * CC * WOUT * 2);
  bf16_t* hb    = (bf16_t*)carve((size_t)NN * WOUT * 2);

  bf16_t* Ha = S1;
  bf16_t* XWdT = (bf16_t*)((char*)S1);
  bf16_t* Yt   = (bf16_t*)((char*)S1 + (2LL << 20));
  float*  disv = scal + CC * NN;

  // combine (+merged prep)
  k_combine<<<1664, 256, 0, stream>>>(A, w0a, w0b, w1, Ha, HbT, Hb2T, part,
                                      X, l1w, l2w, gcnw, Xb, l1wb, l2wb, gwT);
  k_s_finish<<<16, 256, 0, stream>>>(part, svec);

  // layer 0 scalars, then GEMM1 with fused normalize -> HnT + deg2/Mdiag partials
  k_deg1<<<dim3(512, 2), 256, 0, stream>>>(svec, Ha, HbT, dinv1, m1);
  k_gemmL<<<dim3(16, 16, 2), 256, 0, stream>>>(Ha, HbT, HnT, dinv1, m1, Hb2T, pd, pmg);
  k_deg2_finish<<<16, 256, 0, stream>>>(pd, pmg, scal);

  // GCN via associativity (tail GEMMs on BM=64 tiles for 2x grid)
  k_gemm<EP_XWDT, 128><<<dim3(16, 4, 1), 256, 0, stream>>>(
      Xb, gwT, XW, nullptr, disv, XWdT, nullptr, WOUT, WIN, WIN, WIN, 0, 0, 0);
  k_gemm<EP_BF16O, 64><<<dim3(4, 32, 2), 256, 0, stream>>>(
      XWdT, HnT, Yt, nullptr, nullptr, nullptr, nullptr, NN, NN, NN, NN,
      (long long)WOUT * NN, N2, (long long)WOUT * NN);
  k_gemm<EP_GCN, 64><<<dim3(32, 4, 2), 256, 0, stream>>>(
      Hb2T, Yt, Xcat, XW, scal, nullptr, gcnb, WOUT, NN, NN, NN,
      N2, (long long)WOUT * NN, 0);

  // MLP with fused bias(+relu)
  k_gemm<EP_BRELU, 64><<<dim3(32, 4, 1), 256, 0, stream>>>(
      Xcat, l1wb, hb, l1b, nullptr, nullptr, nullptr, WOUT, CC * WOUT, CC * WOUT, CC * WOUT, 0, 0, 0);
  k_gemm<EP_BF32, 64><<<dim3(32, 4, 1), 256, 0, stream>>>(
      hb, l2wb, out, l2b, nullptr, nullptr, nullptr, WOUT, WOUT, WOUT, WOUT, 0, 0, 0);
}

// Round 16
// 133.678 us; speedup vs baseline: 1.2334x; 1.0059x over previous
//
#include <hip/hip_runtime.h>
#include <cstdint>
#include <cstddef>

#define NN   2048
#define N2   (2048LL*2048LL)
#define CC   2
#define EE   5
#define WIN  512
#define WOUT 256

typedef __bf16 bf16_t;
typedef __attribute__((ext_vector_type(8))) __bf16 bf16x8;
typedef __attribute__((ext_vector_type(4))) __bf16 bf16x4;
typedef __attribute__((ext_vector_type(4))) float  f32x4;

#define AS1 __attribute__((address_space(1)))
#define AS3 __attribute__((address_space(3)))

// ---------------- combine (+merged prep): single A pass, prefetch-pipelined loads ----------------

__global__ __launch_bounds__(256, 2)
void k_combine(const float* __restrict__ A,
               const float* __restrict__ w0a, const float* __restrict__ w0b,
               const float* __restrict__ w1,
               bf16_t* __restrict__ Ha, bf16_t* __restrict__ HbT,
               bf16_t* __restrict__ Hb2T, float* __restrict__ part,
               const float* __restrict__ X, const float* __restrict__ l1w,
               const float* __restrict__ l2w, const float* __restrict__ gcnw,
               bf16_t* __restrict__ Xb, bf16_t* __restrict__ l1wb,
               bf16_t* __restrict__ l2wb, bf16_t* __restrict__ gwT) {
  __shared__ bf16_t tl[2][64][65];
  __shared__ float cs[2][4][64];
  int bid = blockIdx.x;
  int t = threadIdx.x;

  if (bid >= 1024) {
    int bid2 = bid - 1024;
    if (bid2 < 608) {
      int i = bid2 * 256 + t;
      const float* src; bf16_t* dst; int off;
      if (i < 131072)      { src = X;   dst = Xb;   off = i; }
      else if (i < 147456) { src = l1w; dst = l1wb; off = i - 131072; }
      else                 { src = l2w; dst = l2wb; off = i - 147456; }
      float4 a = ((const float4*)src)[off * 2];
      float4 b = ((const float4*)src)[off * 2 + 1];
      bf16x8 o;
      o[0] = (bf16_t)a.x; o[1] = (bf16_t)a.y; o[2] = (bf16_t)a.z; o[3] = (bf16_t)a.w;
      o[4] = (bf16_t)b.x; o[5] = (bf16_t)b.y; o[6] = (bf16_t)b.z; o[7] = (bf16_t)b.w;
      ((bf16x8*)dst)[off] = o;
    } else {
      int b2 = bid2 - 608;
      int m0 = (b2 & 7) * 64, n0 = (b2 >> 3) * 64;
      int tr = t >> 4, tc = (t & 15) << 2;
      bf16_t (*tile)[65] = (bf16_t (*)[65])&tl[0][0][0];
#pragma unroll
      for (int v = 0; v < 4; ++v) {
        int r = tr + v * 16;
        float4 d = *(const float4*)&gcnw[(long long)(m0 + r) * WOUT + n0 + tc];
        tile[r][tc + 0] = (bf16_t)d.x; tile[r][tc + 1] = (bf16_t)d.y;
        tile[r][tc + 2] = (bf16_t)d.z; tile[r][tc + 3] = (bf16_t)d.w;
      }
      __syncthreads();
#pragma unroll
      for (int v = 0; v < 4; ++v) {
        int r = tr + v * 16;
        bf16x4 o;
        o[0] = tile[tc + 0][r]; o[1] = tile[tc + 1][r];
        o[2] = tile[tc + 2][r]; o[3] = tile[tc + 3][r];
        *(bf16x4*)&gwT[(long long)(n0 + r) * WIN + m0 + tc] = o;
      }
    }
    return;
  }

  float f[3][2][5];
  {
    const float* wp[3] = {w0a, w0b, w1};
#pragma unroll
    for (int w = 0; w < 3; ++w)
#pragma unroll
      for (int c = 0; c < 2; ++c) {
        float x[5], m = -1e30f, s = 0.f;
#pragma unroll
        for (int e = 0; e < 5; ++e) { x[e] = wp[w][c * 5 + e]; m = fmaxf(m, x[e]); }
#pragma unroll
        for (int e = 0; e < 5; ++e) { x[e] = expf(x[e] - m); s += x[e]; }
#pragma unroll
        for (int e = 0; e < 5; ++e) f[w][c][e] = x[e] / s;
      }
  }
  int i0 = (bid >> 5) * 64, j0 = (bid & 31) * 64;
  int tr = t >> 4, tc = (t & 15) << 2;
  int lane = t & 63, wid = t >> 6;
  float cs0[4] = {0, 0, 0, 0}, cs1[4] = {0, 0, 0, 0};
  bf16x4 hb2a[4], hb2b[4];

  float4 q[5];
  {
    const float* b0 = A + (long long)(i0 + tr) * NN + j0 + tc;
#pragma unroll
    for (int e = 0; e < 5; ++e) q[e] = *(const float4*)(b0 + (long long)e * N2);
  }
#pragma unroll
  for (int v = 0; v < 4; ++v) {
    int lr = tr + v * 16;
    long long gi = i0 + lr;
    float av[5][4];
#pragma unroll
    for (int e = 0; e < 5; ++e) {
      av[e][0] = q[e].x; av[e][1] = q[e].y; av[e][2] = q[e].z; av[e][3] = q[e].w;
    }
    if (v < 3) {
      const float* bn = A + (gi + 16) * (long long)NN + j0 + tc;
#pragma unroll
      for (int e = 0; e < 5; ++e) q[e] = *(const float4*)(bn + (long long)e * N2);
    }
    bf16x4 ha0, ha1;
#pragma unroll
    for (int x = 0; x < 4; ++x) {
      float s0 = 0.f, s1 = 0.f, s2 = 0.f, s3 = 0.f, s4 = 0.f, s5 = 0.f;
#pragma unroll
      for (int e = 0; e < 5; ++e) {
        float u = av[e][x];
        s0 += f[0][0][e] * u; s1 += f[0][1][e] * u;
        s2 += f[1][0][e] * u; s3 += f[1][1][e] * u;
        s4 += f[2][0][e] * u; s5 += f[2][1][e] * u;
      }
      ha0[x] = (bf16_t)s0; cs0[x] += (float)ha0[x];
      ha1[x] = (bf16_t)s1; cs1[x] += (float)ha1[x];
      tl[0][lr][tc + x] = (bf16_t)s2; tl[1][lr][tc + x] = (bf16_t)s3;
      hb2a[v][x] = (bf16_t)s4; hb2b[v][x] = (bf16_t)s5;
    }
    *(bf16x4*)&Ha[0 * N2 + gi * NN + j0 + tc] = ha0;
    *(bf16x4*)&Ha[1 * N2 + gi * NN + j0 + tc] = ha1;
  }
#pragma unroll
  for (int x = 0; x < 4; ++x) {
    float a0 = cs0[x], a1 = cs1[x];
    a0 += __shfl_xor(a0, 16, 64); a0 += __shfl_xor(a0, 32, 64);
    a1 += __shfl_xor(a1, 16, 64); a1 += __shfl_xor(a1, 32, 64);
    if ((lane >> 4) == 0) {
      cs[0][wid][(lane & 15) * 4 + x] = a0;
      cs[1][wid][(lane & 15) * 4 + x] = a1;
    }
  }
  __syncthreads();

#pragma unroll
  for (int v = 0; v < 4; ++v) {
    int lr = tr + v * 16;
#pragma unroll
    for (int ch = 0; ch < 2; ++ch) {
      bf16x4 o;
      o[0] = tl[ch][tc + 0][lr]; o[1] = tl[ch][tc + 1][lr];
      o[2] = tl[ch][tc + 2][lr]; o[3] = tl[ch][tc + 3][lr];
      *(bf16x4*)&HbT[(long long)ch * N2 + (long long)(j0 + lr) * NN + i0 + tc] = o;
    }
  }
  if (t < 128) {
    int ch = t >> 6, col = t & 63;
    float s = cs[ch][0][col] + cs[ch][1][col] + cs[ch][2][col] + cs[ch][3][col];
    part[((long long)ch * 32 + (bid >> 5)) * NN + j0 + col] = s;
  }
  __syncthreads();

#pragma unroll
  for (int v = 0; v < 4; ++v) {
    int lr = tr + v * 16;
#pragma unroll
    for (int x = 0; x < 4; ++x) {
      tl[0][lr][tc + x] = hb2a[v][x];
      tl[1][lr][tc + x] = hb2b[v][x];
    }
  }
  __syncthreads();

#pragma unroll
  for (int v = 0; v < 4; ++v) {
    int lr = tr + v * 16;
#pragma unroll
    for (int ch = 0; ch < 2; ++ch) {
      bf16x4 o;
      o[0] = tl[ch][tc + 0][lr]; o[1] = tl[ch][tc + 1][lr];
      o[2] = tl[ch][tc + 2][lr]; o[3] = tl[ch][tc + 3][lr];
      *(bf16x4*)&Hb2T[(long long)ch * N2 + (long long)(j0 + lr) * NN + i0 + tc] = o;
    }
  }
}

__global__ void k_s_finish(const float* __restrict__ part, float* __restrict__ s) {
  int idx = blockIdx.x * 256 + threadIdx.x;
  int c = idx >> 11, k = idx & 2047;
  float acc = 0.f;
#pragma unroll
  for (int ib = 0; ib < 32; ++ib) acc += part[((long long)c * 32 + ib) * NN + k];
  s[idx] = acc;
}

// deg1[c][j] = sum_k (svec[k] - Ha[j,k])*HbT[j,k]  -> dinv1, m1
__global__ void k_deg1(const float* __restrict__ svec, const bf16_t* __restrict__ Arows,
                       const bf16_t* __restrict__ BT,
                       float* __restrict__ out1, float* __restrict__ out2) {
  int c = blockIdx.y;
  int j = blockIdx.x * 4 + (threadIdx.x >> 6);
  int lane = threadIdx.x & 63;
  const bf16_t* a = Arows + (long long)c * N2 + (long long)j * NN;
  const bf16_t* b = BT + (long long)c * N2 + (long long)j * NN;
  const float* s = svec + c * NN;
  float acc_s = 0.f, acc_a = 0.f;
#pragma unroll
  for (int it = 0; it < 4; ++it) {
    int k0 = (lane + it * 64) * 8;
    bf16x8 av = *(const bf16x8*)(a + k0);
    bf16x8 bv = *(const bf16x8*)(b + k0);
    float4 s0 = *(const float4*)(s + k0);
    float4 s1 = *(const float4*)(s + k0 + 4);
    float sv[8] = {s0.x, s0.y, s0.z, s0.w, s1.x, s1.y, s1.z, s1.w};
#pragma unroll
    for (int x = 0; x < 8; ++x) {
      float bx = (float)bv[x];
      acc_s += sv[x] * bx;
      acc_a += (float)av[x] * bx;
    }
  }
#pragma unroll
  for (int o = 32; o > 0; o >>= 1) {
    acc_s += __shfl_xor(acc_s, o, 64);
    acc_a += __shfl_xor(acc_a, o, 64);
  }
  if (lane == 0) {
    float deg = acc_s - acc_a;
    bool nz = (deg != 0.f);
    out1[c * NN + j] = nz ? 1.f / deg : 0.f;
    out2[c * NN + j] = nz ? 1.f : 0.f;
  }
}

__global__ void k_deg2_finish(const float* __restrict__ pd, const float* __restrict__ pm,
                              float* __restrict__ scal) {
  int idx = blockIdx.x * 256 + threadIdx.x;
  int c = idx >> 11, r = idx & 2047;
  float deg = 0.f, md = 0.f;
#pragma unroll
  for (int by = 0; by < 16; ++by) {
    deg += pd[((long long)by * CC + c) * NN + r];
    md  += pm[((long long)by * CC + c) * NN + r];
  }
  bool nz = (deg != 0.f);
  float dis = nz ? 0.70710678118654752f : 1.f;
  scal[c * NN + r] = nz ? dis / deg : 0.f;
  scal[CC * NN + c * NN + r] = dis;
  scal[2 * CC * NN + c * NN + r] = md;
}

// ---------------- GEMM1: 128x128 tile, BK=64 ring-2; epilogue emits HnT + deg2/Mdiag partials ----------------

__global__ __launch_bounds__(256)
void k_gemmL(const bf16_t* __restrict__ A, const bf16_t* __restrict__ B,
             bf16_t* __restrict__ HnT, const float* __restrict__ dinv,
             const float* __restrict__ m1, const bf16_t* __restrict__ Hb2T,
             float* __restrict__ pd, float* __restrict__ pm) {
  __shared__ __align__(16) char smem[65536];
  bf16_t* As = (bf16_t*)smem;
  bf16_t* Bs = (bf16_t*)(smem + 32768);
  bf16_t* tile = (bf16_t*)smem;
  float* sbd = (float*)(smem + 34816);
  float* sbm = (float*)(smem + 34816 + 1024);

  int cz = blockIdx.z;
  const bf16_t* Ab = A + cz * N2 + (long long)blockIdx.x * 128 * NN;
  const bf16_t* Bb = B + cz * N2 + (long long)blockIdx.y * 128 * NN;

  int t = threadIdx.x, wid = t >> 6, lane = t & 63;
  int wr = wid >> 1, wc = wid & 1;
  f32x4 acc[4][4] = {};
  int frow = lane & 15;
  int fk_sw = (((lane >> 4) ^ ((frow >> 1) & 3)) << 3);
  int srow = t >> 2;
  int scol_sw = (((t & 3) ^ ((t >> 3) & 3)) << 3);

  auto STAGE = [&](int TT, int BUF) {
#pragma unroll
    for (int s = 0; s < 2; ++s) {
      long long kko = (long long)TT * 64 + s * 32 + scol_sw;
      const bf16_t* ga0 = Ab + (long long)srow * NN + kko;
      const bf16_t* gb0 = Bb + (long long)srow * NN + kko;
      char* la = smem + BUF * 16384 + s * 8192 + wid * 1024;
      char* lb = smem + 32768 + BUF * 16384 + s * 8192 + wid * 1024;
      __builtin_amdgcn_global_load_lds((AS1 void*)ga0, (AS3 void*)la, 16, 0, 0);
      __builtin_amdgcn_global_load_lds((AS1 void*)(ga0 + 64LL * NN), (AS3 void*)(la + 4096), 16, 0, 0);
      __builtin_amdgcn_global_load_lds((AS1 void*)gb0, (AS3 void*)lb, 16, 0, 0);
      __builtin_amdgcn_global_load_lds((AS1 void*)(gb0 + 64LL * NN), (AS3 void*)(lb + 4096), 16, 0, 0);
    }
  };
  auto COMPUTE = [&](int BUF) {
#pragma unroll
    for (int ks = 0; ks < 2; ++ks) {
      bf16x8 af[4], bfr[4];
#pragma unroll
      for (int m = 0; m < 4; ++m)
        af[m] = *(const bf16x8*)&As[BUF * 8192 + ks * 4096 + (wr * 64 + m * 16 + frow) * 32 + fk_sw];
#pragma unroll
      for (int n = 0; n < 4; ++n)
        bfr[n] = *(const bf16x8*)&Bs[BUF * 8192 + ks * 4096 + (wc * 64 + n * 16 + frow) * 32 + fk_sw];
      __builtin_amdgcn_s_setprio(1);
#pragma unroll
      for (int m = 0; m < 4; ++m)
#pragma unroll
        for (int n = 0; n < 4; ++n)
          acc[m][n] = __builtin_amdgcn_mfma_f32_16x16x32_bf16(af[m], bfr[n], acc[m][n], 0, 0, 0);
      __builtin_amdgcn_s_setprio(0);
    }
  };

  const int nt = 32;
  STAGE(0, 0); STAGE(1, 1);
  for (int tt = 0; tt < nt; ++tt) {
    if (tt < nt - 1) asm volatile("s_waitcnt vmcnt(8)" ::: "memory");
    else             asm volatile("s_waitcnt vmcnt(0)" ::: "memory");
    __builtin_amdgcn_s_barrier();
    __builtin_amdgcn_sched_barrier(0);
    COMPUTE(tt & 1);
    __builtin_amdgcn_s_barrier();
    if (tt + 2 < nt) STAGE(tt + 2, tt & 1);
  }
  __builtin_amdgcn_sched_barrier(0);

  int rl0 = wr * 64 + ((lane >> 4) << 2);
  int cl0 = wc * 64 + (lane & 15);
  int r0 = blockIdx.x * 128 + rl0;
  int c0 = blockIdx.y * 128 + cl0;

  bf16_t* Ct = HnT + cz * N2;
  const bf16_t* Hb2 = Hb2T + cz * N2;
  float dj[4], m1v[4];
#pragma unroll
  for (int n = 0; n < 4; ++n) {
    dj[n] = dinv[cz * NN + c0 + n * 16];
    m1v[n] = m1[cz * NN + c0 + n * 16];
  }

  float pdeg[4][4], pmd[4][4];
#pragma unroll
  for (int m = 0; m < 4; ++m)
#pragma unroll
    for (int j = 0; j < 4; ++j) {
      int r = r0 + m * 16 + j;
      const bf16_t* hrow = Hb2 + (long long)r * NN;
      float ad = 0.f, am = 0.f;
#pragma unroll
      for (int n = 0; n < 4; ++n) {
        int col = c0 + n * 16;
        float hv = (r == col) ? 0.f : (float)(bf16_t)(acc[m][n][j] * dj[n]);
        float hb = (float)hrow[col];
        am += hv * hb;
        ad += (m1v[n] - hv) * hb;
      }
      pdeg[m][j] = ad; pmd[m][j] = am;
    }
#pragma unroll
  for (int m = 0; m < 4; ++m)
#pragma unroll
    for (int j = 0; j < 4; ++j) {
#pragma unroll
      for (int msk = 1; msk <= 8; msk <<= 1) {
        pdeg[m][j] += __shfl_xor(pdeg[m][j], msk, 64);
        pmd[m][j]  += __shfl_xor(pmd[m][j], msk, 64);
      }
    }
  if ((lane & 15) == 0) {
#pragma unroll
    for (int m = 0; m < 4; ++m)
#pragma unroll
      for (int j = 0; j < 4; ++j) {
        int lrw = m * 16 + ((lane >> 4) << 2) + j;
        sbd[wid * 64 + lrw] = pdeg[m][j];
        sbm[wid * 64 + lrw] = pmd[m][j];
      }
  }
  __syncthreads();
  if (t < 128) {
    int wrof = t >> 6, lr6 = t & 63;
    float dsum = sbd[(wrof * 2 + 0) * 64 + lr6] + sbd[(wrof * 2 + 1) * 64 + lr6];
    float msum = sbm[(wrof * 2 + 0) * 64 + lr6] + sbm[(wrof * 2 + 1) * 64 + lr6];
    long long r = (long long)blockIdx.x * 128 + t;
    pd[((long long)blockIdx.y * CC + cz) * NN + r] = dsum;
    pm[((long long)blockIdx.y * CC + cz) * NN + r] = msum;
  }

#pragma unroll
  for (int m = 0; m < 4; ++m)
#pragma unroll
    for (int n = 0; n < 4; ++n)
#pragma unroll
      for (int j = 0; j < 4; ++j) {
        int r = r0 + m * 16 + j, col = c0 + n * 16;
        float v = (r == col) ? 0.f : acc[m][n][j] * dj[n];
        tile[(rl0 + m * 16 + j) * 130 + cl0 + n * 16] = (bf16_t)v;
      }
  __syncthreads();
  int nl = t >> 5, rl = (t & 31) * 4;
#pragma unroll
  for (int vv = 0; vv < 16; ++vv) {
    int n_l = nl + vv * 8;
    bf16x4 o;
    o[0] = tile[(rl + 0) * 130 + n_l]; o[1] = tile[(rl + 1) * 130 + n_l];
    o[2] = tile[(rl + 2) * 130 + n_l]; o[3] = tile[(rl + 3) * 130 + n_l];
    *(bf16x4*)&Ct[(long long)(blockIdx.y * 128 + n_l) * NN + blockIdx.x * 128 + rl] = o;
  }
}

// ---------------- bf16 GEMM, BMx64 tile (BM=128 or 64), ring-3, counted vmcnt, swizzle ----------------

enum { EP_BRELU = 3, EP_BF32 = 4, EP_BF16O = 7, EP_XWDT = 8, EP_GCN = 9 };

template<int EP, int BM>
__global__ __launch_bounds__(256)
void k_gemm(const bf16_t* __restrict__ A, const bf16_t* __restrict__ B,
            void* __restrict__ Cv,
            const float* __restrict__ aux1, const float* __restrict__ aux2,
            bf16_t* __restrict__ aux3, const float* __restrict__ aux4,
            int N, int K, int lda, int ldb,
            long long zA, long long zB, long long zC) {
  constexpr int MM = BM / 32;                 // per-wave m-fragments
  constexpr int ASLOT = BM * 64;              // A slot bytes (BM x 32 bf16)
  constexpr int BBASE = 3 * ASLOT;            // Bs base byte offset
  __shared__ __align__(16) char smem[BBASE + 3 * 4096 > 36864 ? BBASE + 3 * 4096 : 36864];
  bf16_t* As = (bf16_t*)smem;
  bf16_t* Bs = (bf16_t*)(smem + BBASE);
  bf16_t* tile = (bf16_t*)smem;

  int cz = blockIdx.z;
  const bf16_t* Ab = A + cz * zA + (long long)blockIdx.x * BM * lda;
  const bf16_t* Bb = B + cz * zB + (long long)blockIdx.y * 64 * ldb;

  int t = threadIdx.x, wid = t >> 6, lane = t & 63;
  int wr = wid >> 1, wc = wid & 1;
  f32x4 acc[MM][2] = {};
  int frow = lane & 15;
  int fk_sw = (((lane >> 4) ^ ((frow >> 1) & 3)) << 3);
  int srow = t >> 2;
  int scol_sw = (((t & 3) ^ ((t >> 3) & 3)) << 3);
  int nt = K >> 5;

  auto STAGE = [&](int TT, int BUF) {
    long long kko = (long long)TT * 32 + scol_sw;
    const bf16_t* ga0 = Ab + (long long)srow * lda + kko;
    const bf16_t* gb0 = Bb + (long long)srow * ldb + kko;
    char* la = smem + BUF * ASLOT + wid * 1024;
    char* lb = smem + BBASE + BUF * 4096 + wid * 1024;
    __builtin_amdgcn_global_load_lds((AS1 void*)ga0, (AS3 void*)la, 16, 0, 0);
    if constexpr (BM == 128)
      __builtin_amdgcn_global_load_lds((AS1 void*)(ga0 + 64LL * lda), (AS3 void*)(la + 4096), 16, 0, 0);
    __builtin_amdgcn_global_load_lds((AS1 void*)gb0, (AS3 void*)lb, 16, 0, 0);
  };
  auto COMPUTE = [&](int BUF) {
    bf16x8 af[MM], bfr[2];
#pragma unroll
    for (int m = 0; m < MM; ++m)
      af[m] = *(const bf16x8*)&As[BUF * (ASLOT / 2) + (wr * (BM / 2) + m * 16 + frow) * 32 + fk_sw];
#pragma unroll
    for (int n = 0; n < 2; ++n)
      bfr[n] = *(const bf16x8*)&Bs[BUF * 2048 + (wc * 32 + n * 16 + frow) * 32 + fk_sw];
#pragma unroll
    for (int m = 0; m < MM; ++m)
#pragma unroll
      for (int n = 0; n < 2; ++n)
        acc[m][n] = __builtin_amdgcn_mfma_f32_16x16x32_bf16(af[m], bfr[n], acc[m][n], 0, 0, 0);
  };

  STAGE(0, 0); STAGE(1, 1); STAGE(2, 2);
  int slot = 0;
  for (int tt = 0; tt < nt; ++tt) {
    int rem = nt - 1 - tt;
    if constexpr (BM == 128) {
      if (rem >= 2)      asm volatile("s_waitcnt vmcnt(6)" ::: "memory");
      else if (rem == 1) asm volatile("s_waitcnt vmcnt(3)" ::: "memory");
      else               asm volatile("s_waitcnt vmcnt(0)" ::: "memory");
    } else {
      if (rem >= 2)      asm volatile("s_waitcnt vmcnt(4)" ::: "memory");
      else if (rem == 1) asm volatile("s_waitcnt vmcnt(2)" ::: "memory");
      else               asm volatile("s_waitcnt vmcnt(0)" ::: "memory");
    }
    __builtin_amdgcn_s_barrier();
    __builtin_amdgcn_sched_barrier(0);
    COMPUTE(slot);
    __builtin_amdgcn_s_barrier();
    if (tt + 3 < nt) STAGE(tt + 3, slot);
    slot = (slot == 2) ? 0 : slot + 1;
  }
  __builtin_amdgcn_sched_barrier(0);

  int rl0 = wr * (BM / 2) + ((lane >> 4) << 2);
  int cl0 = wc * 32 + (lane & 15);
  int r0 = blockIdx.x * BM + rl0;
  int c0 = blockIdx.y * 64 + cl0;

  if constexpr (EP == EP_BF16O) {
    bf16_t* Cb = (bf16_t*)Cv + cz * zC;
#pragma unroll
    for (int m = 0; m < MM; ++m)
#pragma unroll
      for (int n = 0; n < 2; ++n)
#pragma unroll
        for (int j = 0; j < 4; ++j)
          Cb[(long long)(r0 + m * 16 + j) * N + c0 + n * 16] = (bf16_t)acc[m][n][j];
  } else if constexpr (EP == EP_XWDT) {
    float* Cb = (float*)Cv;
#pragma unroll
    for (int m = 0; m < MM; ++m)
#pragma unroll
      for (int n = 0; n < 2; ++n)
#pragma unroll
        for (int j = 0; j < 4; ++j) {
          float v = acc[m][n][j];
          Cb[(long long)(r0 + m * 16 + j) * N + c0 + n * 16] = v;
          tile[(rl0 + m * 16 + j) * 65 + cl0 + n * 16] = (bf16_t)v;
        }
    __syncthreads();
    int nl = t >> 5, rl = (t & 31) * 4;
#pragma unroll
    for (int vv = 0; vv < 8; ++vv) {
      int n_l = nl + vv * 8;
      bf16x4 v4;
      v4[0] = tile[(rl + 0) * 65 + n_l]; v4[1] = tile[(rl + 1) * 65 + n_l];
      v4[2] = tile[(rl + 2) * 65 + n_l]; v4[3] = tile[(rl + 3) * 65 + n_l];
      int i0 = blockIdx.x * BM + rl;
      long long row = (long long)(blockIdx.y * 64 + n_l) * NN + i0;
#pragma unroll
      for (int c = 0; c < 2; ++c) {
        float4 dv = *(const float4*)&aux2[c * NN + i0];  // disv
        bf16x4 o;
        o[0] = (bf16_t)((float)v4[0] * dv.x); o[1] = (bf16_t)((float)v4[1] * dv.y);
        o[2] = (bf16_t)((float)v4[2] * dv.z); o[3] = (bf16_t)((float)v4[3] * dv.w);
        *(bf16x4*)&aux3[(long long)c * WOUT * NN + row] = o;
      }
    }
  } else if constexpr (EP == EP_GCN) {
    bf16_t* Cb = (bf16_t*)Cv;
    const float* XWp = aux1;
    const float* csp = aux2 + cz * NN;
    const float* dnp = aux2 + CC * NN + cz * NN;
    const float* mdp = aux2 + 2 * CC * NN + cz * NN;
    float bj[2];
#pragma unroll
    for (int n = 0; n < 2; ++n) bj[n] = aux4[c0 + n * 16];
#pragma unroll
    for (int m = 0; m < MM; ++m)
#pragma unroll
      for (int j = 0; j < 4; ++j) {
        int r = r0 + m * 16 + j;
        float csv = csp[r], dnv = dnp[r], mdv = mdp[r];
        float mdd = mdv * dnv, d2 = dnv * dnv;
#pragma unroll
        for (int n = 0; n < 2; ++n) {
          float xw = XWp[(long long)r * WOUT + c0 + n * 16];
          float v = fmaxf(csv * (acc[m][n][j] - mdd * xw) + d2 * xw + bj[n], 0.f);
          Cb[(long long)r * (CC * WOUT) + cz * WOUT + c0 + n * 16] = (bf16_t)v;
        }
      }
  } else if constexpr (EP == EP_BRELU) {
    bf16_t* Cb = (bf16_t*)Cv;
    float bj[2];
#pragma unroll
    for (int n = 0; n < 2; ++n) bj[n] = aux1[c0 + n * 16];
#pragma unroll
    for (int m = 0; m < MM; ++m)
#pragma unroll
      for (int n = 0; n < 2; ++n)
#pragma unroll
        for (int j = 0; j < 4; ++j)
          Cb[(long long)(r0 + m * 16 + j) * N + c0 + n * 16] =
              (bf16_t)fmaxf(acc[m][n][j] + bj[n], 0.f);
  } else { // EP_BF32
    float* Cb = (float*)Cv;
    float bj[2];
#pragma unroll
    for (int n = 0; n < 2; ++n) bj[n] = aux1[c0 + n * 16];
#pragma unroll
    for (int m = 0; m < MM; ++m)
#pragma unroll
      for (int n = 0; n < 2; ++n)
#pragma unroll
        for (int j = 0; j < 4; ++j)
          Cb[(long long)(r0 + m * 16 + j) * N + c0 + n * 16] = acc[m][n][j] + bj[n];
  }
}

// ---------------- launch ----------------

extern "C" void kernel_launch(void* const* d_in, const int* in_sizes, int n_in,
                              void* d_out, int out_size, void* d_ws, size_t ws_size,
                              hipStream_t stream) {
  const float* A    = (const float*)d_in[0];
  const float* X    = (const float*)d_in[1];
  const float* w0a  = (const float*)d_in[2];
  const float* w0b  = (const float*)d_in[3];
  const float* w1   = (const float*)d_in[4];
  const float* gcnw = (const float*)d_in[5];
  const float* gcnb = (const float*)d_in[6];
  const float* l1w  = (const float*)d_in[7];
  const float* l1b  = (const float*)d_in[8];
  const float* l2w  = (const float*)d_in[9];
  const float* l2b  = (const float*)d_in[10];
  float* out = (float*)d_out;

  char* p = (char*)d_ws;
  auto carve = [&](size_t bytes) -> char* {
    char* r = p; p += (bytes + 255) & ~(size_t)255; return r;
  };
  float*  svec  = (float*)carve((size_t)CC * NN * 4);
  float*  dinv1 = (float*)carve((size_t)CC * NN * 4);
  float*  m1    = (float*)carve((size_t)CC * NN * 4);
  float*  scal  = (float*)carve((size_t)3 * CC * NN * 4);   // cscal | disv | Mdiag
  float*  part  = (float*)carve((size_t)CC * 32 * NN * 4);
  float*  pd    = (float*)carve((size_t)16 * CC * NN * 4);
  float*  pmg   = (float*)carve((size_t)16 * CC * NN * 4);
  bf16_t* S1    = (bf16_t*)carve((size_t)CC * N2 * 2);  // Ha -> {XWdT, Yt}
  bf16_t* HbT   = (bf16_t*)carve((size_t)CC * N2 * 2);
  bf16_t* Hb2T  = (bf16_t*)carve((size_t)CC * N2 * 2);
  bf16_t* HnT   = (bf16_t*)carve((size_t)CC * N2 * 2);
  bf16_t* Xb    = (bf16_t*)carve((size_t)NN * WIN * 2);
  bf16_t* gwT   = (bf16_t*)carve((size_t)WOUT * WIN * 2);
  bf16_t* l1wb  = (bf16_t*)carve((size_t)WOUT * CC * WOUT * 2);
  bf16_t* l2wb  = (bf16_t*)carve((size_t)WOUT * WOUT * 2);
  float*  XW    = (float*)carve((size_t)NN * WOUT * 4);
  bf16_t* Xcat  = (bf16_t*)carve((size_t)NN * CC * WOUT * 2);
  bf16_t* hb    = (bf16_t*)carve((size_t)NN * WOUT * 2);

  bf16_t* Ha = S1;
  bf16_t* XWdT = (bf16_t*)((char*)S1);
  bf16_t* Yt   = (bf16_t*)((char*)S1 + (2LL << 20));
  float*  disv = scal + CC * NN;

  // combine (+merged prep)
  k_combine<<<1664, 256, 0, stream>>>(A, w0a, w0b, w1, Ha, HbT, Hb2T, part,
                                      X, l1w, l2w, gcnw, Xb, l1wb, l2wb, gwT);
  k_s_finish<<<16, 256, 0, stream>>>(part, svec);

  // layer 0 scalars, then GEMM1 with fused normalize -> HnT + deg2/Mdiag partials
  k_deg1<<<dim3(512, 2), 256, 0, stream>>>(svec, Ha, HbT, dinv1, m1);
  k_gemmL<<<dim3(16, 16, 2), 256, 0, stream>>>(Ha, HbT, HnT, dinv1, m1, Hb2T, pd, pmg);
  k_deg2_finish<<<16, 256, 0, stream>>>(pd, pmg, scal);

  // GCN via associativity (tail GEMMs on BM=64 tiles for 2x grid)
  k_gemm<EP_XWDT, 128><<<dim3(16, 4, 1), 256, 0, stream>>>(
      Xb, gwT, XW, nullptr, disv, XWdT, nullptr, WOUT, WIN, WIN, WIN, 0, 0, 0);
  k_gemm<EP_BF16O, 64><<<dim3(4, 32, 2), 256, 0, stream>>>(
      XWdT, HnT, Yt, nullptr, nullptr, nullptr, nullptr, NN, NN, NN, NN,
      (long long)WOUT * NN, N2, (long long)WOUT * NN);
  k_gemm<EP_GCN, 64><<<dim3(32, 4, 2), 256, 0, stream>>>(
      Hb2T, Yt, Xcat, XW, scal, nullptr, gcnb, WOUT, NN, NN, NN,
      N2, (long long)WOUT * NN, 0);

  // MLP with fused bias(+relu)
  k_gemm<EP_BRELU, 64><<<dim3(32, 4, 1), 256, 0, stream>>>(
      Xcat, l1wb, hb, l1b, nullptr, nullptr, nullptr, WOUT, CC * WOUT, CC * WOUT, CC * WOUT, 0, 0, 0);
  k_gemm<EP_BF32, 64><<<dim3(32, 4, 1), 256, 0, stream>>>(
      hb, l2wb, out, l2b, nullptr, nullptr, nullptr, WOUT, WOUT, WOUT, WOUT, 0, 0, 0);
}